// Round 3
// baseline (470.432 us; speedup 1.0000x reference)
//
#include <hip/hip_runtime.h>
#include <stdint.h>

// ConcatLayer_55654186221983 on MI355X (gfx950). All fp32 I/O.
// B=8, C=128, C2=256, H=W=64, EMB=512, GROUPS=32, EPS=1e-5.
// R12: single kernel, software global barrier (graph-capture-proof; coop
//      grid.sync broke under capture in R11). 512 blocks = exact capacity
//      (2/CU: LDS 54.9KB, VGPR<=256). P4 folded into P3 epilogue (no y3
//      round-trip). Barrier: monotonic u64 counters + MAGIC-guarded init
//      (robust to per-iteration workspace poison AND to replay w/o poison).

#define B_   8
#define C_   128
#define C2_  256
#define HW_  4096
#define EMB_ 512
#define EPS_ 1e-5f
#define NBLK_ 512
#define MAGIC_ 0x5CA1AB1EF00DFEEDULL

typedef int   v16i __attribute__((ext_vector_type(16)));
typedef float v16f __attribute__((ext_vector_type(16)));
typedef short v8s  __attribute__((ext_vector_type(8)));
typedef int   v4i  __attribute__((ext_vector_type(4)));

// LDS tile: 3 rows x 66 cols x (256 data + 16 pad) bytes
#define COLB 272
#define LDSZ (3 * 66 * COLB)

__device__ __forceinline__ float silu(float v) {
    return v * __builtin_amdgcn_rcpf(1.f + __expf(-v));
}
__device__ __forceinline__ unsigned short f2bf(float f) {
    unsigned int x = __float_as_uint(f);
    return (unsigned short)((x + 0x7FFFu + ((x >> 16) & 1u)) >> 16);  // RNE
}
__device__ __forceinline__ int8_t sgn8(float v) {
    return (v > 0.f) ? (int8_t)1 : ((v < 0.f) ? (int8_t)(-1) : (int8_t)0);
}

// ---- software global barrier (device-scope, graph-capture safe) ----
// Monotonic counter + round arithmetic: works across graph replays without
// reset. 'ready' MAGIC gate: block 0 re-zeroes counters only after workspace
// poison (ready != MAGIC); all blocks wait for MAGIC before first arrival.
__device__ __forceinline__ void gbarrier(unsigned long long* ready,
                                         unsigned long long* cnt) {
    __syncthreads();
    if (threadIdx.x == 0) {
        __threadfence();   // write back my XCD's L2 (producer side)
        while (__hip_atomic_load(ready, __ATOMIC_ACQUIRE,
                                 __HIP_MEMORY_SCOPE_AGENT) != MAGIC_)
            __builtin_amdgcn_s_sleep(2);
        unsigned long long v = __hip_atomic_fetch_add(
            cnt, 1ULL, __ATOMIC_ACQ_REL, __HIP_MEMORY_SCOPE_AGENT);
        unsigned long long target = (v / NBLK_ + 1ULL) * (unsigned long long)NBLK_;
        while (__hip_atomic_load(cnt, __ATOMIC_RELAXED,
                                 __HIP_MEMORY_SCOPE_AGENT) < target)
            __builtin_amdgcn_s_sleep(2);
        __threadfence();   // invalidate my XCD's L2 (consumer side)
    }
    __syncthreads();
}

__global__ __launch_bounds__(256, 2) void k_fused(
    const float* __restrict__ cin, const float* __restrict__ xin,
    const float* __restrict__ emb,
    const float* __restrict__ g1w, const float* __restrict__ g1b,
    const float* __restrict__ w1, const float* __restrict__ c1b,
    const float* __restrict__ ew, const float* __restrict__ ebb,
    const float* __restrict__ g2w, const float* __restrict__ g2b,
    const float* __restrict__ w2, const float* __restrict__ c2b,
    const float* __restrict__ m1w, const float* __restrict__ m1b,
    const float* __restrict__ wq, const float* __restrict__ bqb,
    const float* __restrict__ bng, const float* __restrict__ bnb,
    const float* __restrict__ m2w, const float* __restrict__ m2b,
    const float* __restrict__ pa,
    const float* __restrict__ m3w, const float* __restrict__ m3b,
    float* __restrict__ out, float* __restrict__ ws) {
    __shared__ __align__(16) char lds[LDSZ];
    __shared__ float ldsA[128], ldsB[128];

    // ---- workspace layout ----
    const size_t NCHW = (size_t)B_ * C_ * HW_;   // 4,194,304
    float* poolC2 = ws;
    float* y_buf  = ws + NCHW;                                 // conv1 out
    unsigned short* actA = (unsigned short*)(ws + 2 * NCHW);   // bf16 NHWC
    int8_t* S     = (int8_t*)(ws + 2 * NCHW);                  // aliases actA
    int8_t* sgn   = (int8_t*)(ws + 2 * NCHW + NCHW / 2);
    unsigned short* Wc1 = (unsigned short*)(ws + 2 * NCHW + NCHW / 2 + 73728);
    unsigned short* Wc2 = Wc1 + C_ * C_ * 9;
    float* alpha = ws + 2 * NCHW + NCHW / 2 + 73728 + 2 * 73728;
    float* eo    = alpha + 128;
    float* b1v   = eo + B_ * 256;
    float* b2v   = b1v + B_ * 256;
    float* b3v   = b2v + B_ * 128;
    float* bnS   = b3v + B_ * 128;
    float* bnQ   = bnS + 128;
    float* gnS   = bnQ + 128;   // 256
    float* gnQ   = gnS + 256;   // 256
    unsigned long long* bar = (unsigned long long*)(gnQ + 256); // ready + cnt[4]
    unsigned long long* ready = bar;
    unsigned long long* cnt   = bar + 1;

    const int blk = blockIdx.x;
    const int tid = threadIdx.x;

    // ---- barrier init (block 0): only needed after workspace poison ----
    if (blk == 0 && tid == 0) {
        if (__hip_atomic_load(ready, __ATOMIC_RELAXED,
                              __HIP_MEMORY_SCOPE_AGENT) != MAGIC_) {
            for (int i = 0; i < 4; ++i)
                __hip_atomic_store(&cnt[i], 0ULL, __ATOMIC_RELAXED,
                                   __HIP_MEMORY_SCOPE_AGENT);
            __hip_atomic_store(ready, MAGIC_, __ATOMIC_RELEASE,
                               __HIP_MEMORY_SCOPE_AGENT);
        }
    }

    // ============ P0: prep (GN1, binary weights, relayout, emb MLPs) ============
    if (blk < 256) {
        // GN1: one block per (n,grp), shfl reduction; writes actA bf16 NHWC
        float* red = (float*)lds;
        const int n = blk >> 5, grp = blk & 31;
        const size_t base = ((size_t)(n * C_ + grp * 4)) << 12;
        float sum = 0.f, sq = 0.f;
        const float4* in4 = (const float4*)(cin + base);
        for (int i = tid; i < 4096; i += 256) {
            float4 v = in4[i];
            sum += v.x + v.y + v.z + v.w;
            sq += v.x * v.x + v.y * v.y + v.z * v.z + v.w * v.w;
        }
#pragma unroll
        for (int off = 32; off > 0; off >>= 1) {
            sum += __shfl_xor(sum, off, 64);
            sq  += __shfl_xor(sq, off, 64);
        }
        if ((tid & 63) == 0) { red[tid >> 6] = sum; red[8 + (tid >> 6)] = sq; }
        __syncthreads();
        sum = red[0] + red[1] + red[2] + red[3];
        sq  = red[8] + red[9] + red[10] + red[11];
        const float mu = sum * (1.f / 16384.f);
        const float rstd = rsqrtf(sq * (1.f / 16384.f) - mu * mu + EPS_);
        float gg[4], bb4[4];
#pragma unroll
        for (int j = 0; j < 4; ++j) { gg[j] = g1w[grp * 4 + j]; bb4[j] = g1b[grp * 4 + j]; }
        for (int hw = tid; hw < HW_; hw += 256) {
            union { unsigned short u[4]; uint2 v; } pk;
#pragma unroll
            for (int j = 0; j < 4; ++j) {
                float v = cin[base + ((size_t)j << 12) + hw];
                pk.u[j] = f2bf(silu((v - mu) * rstd * gg[j] + bb4[j]));
            }
            *(uint2*)(actA + ((size_t)(n * HW_ + hw)) * C_ + grp * 4) = pk.v;
        }
    } else if (blk < 384) {
        // binary-conv weights: sign + alpha; also zero the stat accumulators
        float* red = (float*)lds;
        const int o = blk - 256;
        if (o == 0 && tid < 128) { bnS[tid] = 0.f; bnQ[tid] = 0.f; }
        if (o == 1) gnS[tid] = 0.f;
        if (o == 2) gnQ[tid] = 0.f;
        const float* wr = wq + (size_t)o * (C2_ * 9);
        float s = 0.f;
        for (int i = tid; i < C2_ * 9; i += 256) s += fabsf(wr[i]);
        red[tid] = s;
        __syncthreads();
        for (int st = 128; st > 0; st >>= 1) {
            if (tid < st) red[tid] += red[tid + st];
            __syncthreads();
        }
        if (tid == 0) alpha[o] = red[0] / (float)(C2_ * 9);
        for (int kk = 0; kk < 9; ++kk) {
            float v = wr[tid * 9 + kk];   // tid == ci
            sgn[((size_t)(kk * 16 + (tid >> 4)) * C_ + o) * 16 + (tid & 15)] = sgn8(v);
        }
    } else {
        // conv1/conv2 weight relayout (grid-stride over 128 blocks)
        for (int i = (blk - 384) * 256 + tid; i < C_ * C_ * 9; i += 128 * 256) {
            int co = i / (C_ * 9);
            int rem = i - co * (C_ * 9);
            int ci = rem / 9, kk = rem - ci * 9;
            size_t d = ((size_t)(kk * 16 + (ci >> 3)) * C_ + co) * 8 + (ci & 7);
            Wc1[d] = f2bf(w1[i]);
            Wc2[d] = f2bf(w2[i]);
        }
    }
    if (blk >= 256) {
        // embedding MLPs: wave per output row (768 rows over blocks 256..447)
        const int o = (blk - 256) * 4 + (tid >> 6);
        if (o < 768) {
            const int l = tid & 63;
            const float* wv;
            float bias;
            float* dst;
            int dstride;
            if (o < 256)      { wv = ew  + (size_t)o * EMB_;              bias = ebb[o];    dst = eo + o;   dstride = 256; }
            else if (o < 512) { int r = o - 256; wv = m1w + (size_t)r * EMB_; bias = m1b[r]; dst = b1v + r; dstride = 256; }
            else if (o < 640) { int r = o - 512; wv = m2w + (size_t)r * EMB_; bias = m2b[r]; dst = b2v + r; dstride = 128; }
            else              { int r = o - 640; wv = m3w + (size_t)r * EMB_; bias = m3b[r]; dst = b3v + r; dstride = 128; }
            const float4 wa = *(const float4*)(wv + 8 * l);
            const float4 wb = *(const float4*)(wv + 8 * l + 4);
#pragma unroll
            for (int b = 0; b < B_; ++b) {
                const float* sp = emb + b * EMB_ + 8 * l;
                float4 sa = *(const float4*)(sp);
                float4 sb = *(const float4*)(sp + 4);
                float p = wa.x * silu(sa.x) + wa.y * silu(sa.y) + wa.z * silu(sa.z) + wa.w * silu(sa.w) +
                          wb.x * silu(sb.x) + wb.y * silu(sb.y) + wb.z * silu(sb.z) + wb.w * silu(sb.w);
#pragma unroll
                for (int off = 32; off > 0; off >>= 1) p += __shfl_down(p, off, 64);
                if (l == 0) dst[b * dstride] = bias + p;
            }
        }
    }
    gbarrier(ready, &cnt[0]);

    // ============ P1: conv1 (bf16 MFMA) + fused GN2 stats ============
    {
        const int y = blk & 63;
        const int n = blk >> 6;
        const char* base = (const char*)(actA + ((size_t)n * 64) * 64 * C_);
        {
            const char* rs[3] = {
                (y > 0)  ? base + (size_t)(y - 1) * 16384 : nullptr,
                base + (size_t)y * 16384,
                (y < 63) ? base + (size_t)(y + 1) * 16384 : nullptr };
            if (tid < 96) {
                int r = tid / 32, q = tid & 31;
                int c = (q >> 4) ? 65 : 0, o = q & 15;
                *(float4*)(lds + (r * 66 + c) * COLB + o * 16) = make_float4(0.f, 0.f, 0.f, 0.f);
            }
#pragma unroll
            for (int u = 0; u < 12; ++u) {
                int idx = u * 256 + tid;
                int r = idx >> 10, rem = idx & 1023;
                int x = rem >> 4, o = rem & 15;
                char* dst = lds + (r * 66 + x + 1) * COLB + o * 16;
                if (rs[r]) *(float4*)dst = *(const float4*)(rs[r] + x * 256 + o * 16);
                else       *(float4*)dst = make_float4(0.f, 0.f, 0.f, 0.f);
            }
        }
        __syncthreads();

        const int w = tid >> 6;
        const int l = tid & 63;
        const int lm = l & 31;
        const int lh = l >> 5;

        v16f acc0, acc1;
#pragma unroll
        for (int i = 0; i < 16; ++i) { acc0[i] = 0.f; acc1[i] = 0.f; }

#pragma unroll
        for (int kk = 0; kk < 9; ++kk) {
            const int r = kk / 3, dx = kk % 3 - 1;
            const char* col0 = lds + (r * 66 + lm + 1 + dx) * COLB + 16 * lh;
            const char* col1 = col0 + 32 * COLB;
            const unsigned short* wbase = Wc1 + (size_t)(kk * 16 + lh) * C_ * 8 + (32 * w + lm) * 8;
#pragma unroll
            for (int cb = 0; cb < 8; ++cb) {
                v8s a = *(const v8s*)(wbase + (size_t)(2 * cb) * C_ * 8);
                v8s b0 = *(const v8s*)(col0 + 32 * cb);
                v8s b1 = *(const v8s*)(col1 + 32 * cb);
                acc0 = __builtin_amdgcn_mfma_f32_32x32x16_bf16(a, b0, acc0, 0, 0, 0);
                acc1 = __builtin_amdgcn_mfma_f32_32x32x16_bf16(a, b1, acc1, 0, 0, 0);
            }
        }
        float pr[16], qr[16];
#pragma unroll
        for (int r = 0; r < 16; ++r) {
            const int row = (r & 3) + 8 * (r >> 2) + 4 * lh;
            const int co = 32 * w + row;
            const float bv = c1b[co];
            const size_t o = (((size_t)n * C_ + co) << 12) + (y << 6);
            float v0 = acc0[r] + bv, v1 = acc1[r] + bv;
            y_buf[o + lm] = v0;
            y_buf[o + 32 + lm] = v1;
            pr[r] = v0 + v1;
            qr[r] = v0 * v0 + v1 * v1;
        }
        __syncthreads();
        float* ldsS = (float*)lds;
        float* ldsQ = (float*)lds + 128;
#pragma unroll
        for (int r = 0; r < 16; ++r) {
            float p = pr[r], q = qr[r];
#pragma unroll
            for (int m = 16; m > 0; m >>= 1) {
                p += __shfl_xor(p, m, 64);
                q += __shfl_xor(q, m, 64);
            }
            if (lm == 0) {
                const int row = (r & 3) + 8 * (r >> 2) + 4 * lh;
                const int co = 32 * w + row;
                ldsS[co] = p;
                ldsQ[co] = q;
            }
        }
        __syncthreads();
        if (tid < 32) {
            const int g = tid;
            float p = ldsS[4 * g] + ldsS[4 * g + 1] + ldsS[4 * g + 2] + ldsS[4 * g + 3];
            float q = ldsQ[4 * g] + ldsQ[4 * g + 1] + ldsQ[4 * g + 2] + ldsQ[4 * g + 3];
            atomicAdd(&gnS[n * 32 + g], p);
            atomicAdd(&gnQ[n * 32 + g], q);
        }
    }
    gbarrier(ready, &cnt[1]);

    // ============ P2: conv2 (GN2+FiLM+SiLU in staging) + sign + pool ============
    {
        const int y = blk & 63;
        const int n = blk >> 6;

        if (tid < 128) {
            const int ch = tid, grp = tid >> 2;
            const float mu = gnS[n * 32 + grp] * (1.f / 16384.f);
            const float var = gnQ[n * 32 + grp] * (1.f / 16384.f) - mu * mu;
            const float rstd = rsqrtf(var + EPS_);
            const float gg = g2w[ch] * rstd;
            const float sc = 1.f + eo[n * 256 + ch];
            ldsA[ch] = gg * sc;
            ldsB[ch] = (g2b[ch] - mu * gg) * sc + eo[n * 256 + 128 + ch];
        }
        if (tid < 96) {   // zero pad columns 0 and 65
            int r = tid / 32, q = tid & 31;
            int cpad = (q >> 4) ? 65 : 0, o = q & 15;
            *(float4*)(lds + (r * 66 + cpad) * COLB + o * 16) = make_float4(0.f, 0.f, 0.f, 0.f);
        }
        __syncthreads();

        const float* yb = y_buf + ((size_t)n * C_) * HW_ + (y << 6);
#pragma unroll 4
        for (int u = 0; u < 24; ++u) {
            int unit = u * 256 + tid;
            int r = unit >> 11, rem = unit & 2047;
            int ch = rem >> 4, seg = rem & 15;
            int yy = y - 1 + r;
            char* dst = lds + (r * 66 + 1 + seg) * COLB + ch * 2;
            if (yy >= 0 && yy < 64) {
                const float A = ldsA[ch], Bv = ldsB[ch];
                const float* src = yb + (size_t)ch * HW_ + (r - 1) * 64 + seg;
#pragma unroll
                for (int j = 0; j < 4; ++j)
                    *(unsigned short*)(dst + (16 * j) * COLB) = f2bf(silu(src[16 * j] * A + Bv));
            } else {
#pragma unroll
                for (int j = 0; j < 4; ++j)
                    *(unsigned short*)(dst + (16 * j) * COLB) = 0;
            }
        }
        __syncthreads();

        const int w = tid >> 6;
        const int l = tid & 63;
        const int lm = l & 31;
        const int lh = l >> 5;

        v16f acc0, acc1;
#pragma unroll
        for (int i = 0; i < 16; ++i) { acc0[i] = 0.f; acc1[i] = 0.f; }

#pragma unroll
        for (int kk = 0; kk < 9; ++kk) {
            const int r = kk / 3, dx = kk % 3 - 1;
            const char* col0 = lds + (r * 66 + lm + 1 + dx) * COLB + 16 * lh;
            const char* col1 = col0 + 32 * COLB;
            const unsigned short* wbase = Wc2 + (size_t)(kk * 16 + lh) * C_ * 8 + (32 * w + lm) * 8;
#pragma unroll
            for (int cb = 0; cb < 8; ++cb) {
                v8s a = *(const v8s*)(wbase + (size_t)(2 * cb) * C_ * 8);
                v8s b0 = *(const v8s*)(col0 + 32 * cb);
                v8s b1 = *(const v8s*)(col1 + 32 * cb);
                acc0 = __builtin_amdgcn_mfma_f32_32x32x16_bf16(a, b0, acc0, 0, 0, 0);
                acc1 = __builtin_amdgcn_mfma_f32_32x32x16_bf16(a, b1, acc1, 0, 0, 0);
            }
        }
        float c2v0[16], c2v1[16];
#pragma unroll
        for (int r = 0; r < 16; ++r) {
            const int row = (r & 3) + 8 * (r >> 2) + 4 * lh;
            const int co = 32 * w + row;
            const float bv = c2b[co];
            const size_t o = (((size_t)n * C_ + co) << 12) + (y << 6);
            c2v0[r] = acc0[r] + bv + cin[o + lm];
            c2v1[r] = acc1[r] + bv + cin[o + 32 + lm];
        }
        // pooled c2-half (channel-pair means), in-register
#pragma unroll
        for (int q = 0; q < 4; ++q) {
            const int pc = 16 * w + 4 * q + 2 * lh;   // pooled channel (0..63)
            const size_t po = (((size_t)n * 64 + pc) << 12) + (y << 6);
            poolC2[po + lm]             = 0.5f * (c2v0[4 * q] + c2v0[4 * q + 1]);
            poolC2[po + 32 + lm]        = 0.5f * (c2v1[4 * q] + c2v1[4 * q + 1]);
            poolC2[po + 4096 + lm]      = 0.5f * (c2v0[4 * q + 2] + c2v0[4 * q + 3]);
            poolC2[po + 4096 + 32 + lm] = 0.5f * (c2v1[4 * q + 2] + c2v1[4 * q + 3]);
        }

        // fused sign: build S row [64 px][256 ch] bytes in LDS, then store
        __syncthreads();
#pragma unroll
        for (int q = 0; q < 4; ++q) {
            const int co0 = 32 * w + 8 * q + 4 * lh;
            const float b0 = b1v[n * 256 + 128 + co0];
            const float b1b = b1v[n * 256 + 128 + co0 + 1];
            const float b2b = b1v[n * 256 + 128 + co0 + 2];
            const float b3b = b1v[n * 256 + 128 + co0 + 3];
            union { int8_t b[4]; int u; } p0, p1;
            p0.b[0] = sgn8(c2v0[4 * q] + b0);      p1.b[0] = sgn8(c2v1[4 * q] + b0);
            p0.b[1] = sgn8(c2v0[4 * q + 1] + b1b); p1.b[1] = sgn8(c2v1[4 * q + 1] + b1b);
            p0.b[2] = sgn8(c2v0[4 * q + 2] + b2b); p1.b[2] = sgn8(c2v1[4 * q + 2] + b2b);
            p0.b[3] = sgn8(c2v0[4 * q + 3] + b3b); p1.b[3] = sgn8(c2v1[4 * q + 3] + b3b);
            *(int*)(lds + lm * COLB + 128 + co0) = p0.u;
            *(int*)(lds + (32 + lm) * COLB + 128 + co0) = p1.u;
        }
#pragma unroll
        for (int u = 0; u < 8; ++u) {
            int idx = u * 256 + tid;
            int ch = idx >> 4, seg = idx & 15;
            float4 v = *(const float4*)(xin + (((size_t)(n * C_ + ch)) << 12) + (y << 6) + 4 * seg);
            const float bv = b1v[n * 256 + ch];
            lds[(4 * seg) * COLB + ch]     = sgn8(v.x + bv);
            lds[(4 * seg + 1) * COLB + ch] = sgn8(v.y + bv);
            lds[(4 * seg + 2) * COLB + ch] = sgn8(v.z + bv);
            lds[(4 * seg + 3) * COLB + ch] = sgn8(v.w + bv);
        }
        __syncthreads();
        int8_t* Srow = S + ((size_t)(n * HW_) + (y << 6)) * C2_;
#pragma unroll
        for (int u = 0; u < 4; ++u) {
            int idx = u * 256 + tid;
            int px = idx >> 4, c16 = idx & 15;
            *(int4*)(Srow + (size_t)px * C2_ + 16 * c16) = *(const int4*)(lds + px * COLB + 16 * c16);
        }
    }
    gbarrier(ready, &cnt[2]);

    // ============ P3: binary conv (i8 MFMA) + BN stats + folded final ============
    {
        const int y = blk & 63;
        const int n = blk >> 6;
        const char* base = (const char*)(S + ((size_t)n * 64) * 64 * C2_);
        {
            const char* rs[3] = {
                (y > 0)  ? base + (size_t)(y - 1) * 16384 : nullptr,
                base + (size_t)y * 16384,
                (y < 63) ? base + (size_t)(y + 1) * 16384 : nullptr };
            if (tid < 96) {
                int r = tid / 32, q = tid & 31;
                int c = (q >> 4) ? 65 : 0, o = q & 15;
                *(float4*)(lds + (r * 66 + c) * COLB + o * 16) = make_float4(0.f, 0.f, 0.f, 0.f);
            }
#pragma unroll
            for (int u = 0; u < 12; ++u) {
                int idx = u * 256 + tid;
                int r = idx >> 10, rem = idx & 1023;
                int x = rem >> 4, o = rem & 15;
                char* dst = lds + (r * 66 + x + 1) * COLB + o * 16;
                if (rs[r]) *(float4*)dst = *(const float4*)(rs[r] + x * 256 + o * 16);
                else       *(float4*)dst = make_float4(0.f, 0.f, 0.f, 0.f);
            }
        }
        __syncthreads();

        const int w = tid >> 6;
        const int l = tid & 63;
        const int lm = l & 31;
        const int lh = l >> 5;

        v16i acc0, acc1;
#pragma unroll
        for (int i = 0; i < 16; ++i) { acc0[i] = 0; acc1[i] = 0; }

#pragma unroll
        for (int kk = 0; kk < 9; ++kk) {
            const int r = kk / 3, dx = kk % 3 - 1;
            const char* col0 = lds + (r * 66 + lm + 1 + dx) * COLB + 16 * lh;
            const char* col1 = col0 + 32 * COLB;
            const int8_t* wbase = sgn + (size_t)(kk * 16 + lh) * C_ * 16 + (32 * w + lm) * 16;
#pragma unroll
            for (int s = 0; s < 8; ++s) {
                v4i a = *(const v4i*)(wbase + (size_t)(2 * s) * C_ * 16);
                v4i b0 = *(const v4i*)(col0 + 32 * s);
                v4i b1 = *(const v4i*)(col1 + 32 * s);
                acc0 = __builtin_amdgcn_mfma_i32_32x32x32_i8(a, b0, acc0, 0, 0, 0);
                acc1 = __builtin_amdgcn_mfma_i32_32x32x32_i8(a, b1, acc1, 0, 0, 0);
            }
        }

        float bv0[16], bv1[16], pr[16], qr[16];
#pragma unroll
        for (int r = 0; r < 16; ++r) {
            const int row = (r & 3) + 8 * (r >> 2) + 4 * lh;
            const int co = 32 * w + row;
            const float av = alpha[co], bv = bqb[co];
            float v0 = av * (float)acc0[r] + bv;
            float v1 = av * (float)acc1[r] + bv;
            bv0[r] = v0;
            bv1[r] = v1;
            pr[r] = v0 + v1;
            qr[r] = v0 * v0 + v1 * v1;
        }
        __syncthreads();
        float* ldsS = (float*)lds;
        float* ldsQ = (float*)lds + 128;
#pragma unroll
        for (int r = 0; r < 16; ++r) {
            float p = pr[r], q = qr[r];
#pragma unroll
            for (int m = 16; m > 0; m >>= 1) {
                p += __shfl_xor(p, m, 64);
                q += __shfl_xor(q, m, 64);
            }
            if (lm == 0) {
                const int row = (r & 3) + 8 * (r >> 2) + 4 * lh;
                const int co = 32 * w + row;
                ldsS[co] = p;
                ldsQ[co] = q;
            }
        }
        __syncthreads();
        if (tid < 128) {
            atomicAdd(&bnS[tid], ldsS[tid]);
            atomicAdd(&bnQ[tid], ldsQ[tid]);
        }
        gbarrier(ready, &cnt[3]);

        // ---- folded final: BN affine + pooling + PReLU + biases -> out ----
        float* ldsG  = (float*)lds;
        float* ldsBt = (float*)lds + 128;
        if (tid < 128) {
            const int co = tid;
            const float mu = bnS[co] * (1.f / 32768.f);
            const float var = bnQ[co] * (1.f / 32768.f) - mu * mu;
            const float rstd = rsqrtf(var + EPS_);
            const float gm = rstd * bng[co];
            ldsG[co]  = gm;
            ldsBt[co] = bnb[co] - mu * gm;
        }
        __syncthreads();
#pragma unroll
        for (int r = 0; r < 16; ++r) {
            const int row = (r & 3) + 8 * (r >> 2) + 4 * lh;
            const int co = 32 * w + row;
            const float gm = ldsG[co], bt = ldsBt[co];
            float t0 = bv0[r] * gm + bt;
            float t1 = bv1[r] * gm + bt;
            float p0, p1;
            if (co < 64) {
                const size_t xb = (((size_t)(n * C_ + 2 * co)) << 12) + (y << 6);
                p0 = 0.5f * (xin[xb + lm] + xin[xb + 4096 + lm]);
                p1 = 0.5f * (xin[xb + 32 + lm] + xin[xb + 4096 + 32 + lm]);
            } else {
                const size_t pb = (((size_t)(n * 64 + co - 64)) << 12) + (y << 6);
                p0 = poolC2[pb + lm];
                p1 = poolC2[pb + 32 + lm];
            }
            const float bias2 = b2v[n * 128 + co];
            const float aP = pa[co];
            const float bias3 = b3v[n * 128 + co];
            float o0 = t0 + p0 + bias2; o0 = (o0 >= 0.f) ? o0 : aP * o0; o0 += bias3;
            float o1 = t1 + p1 + bias2; o1 = (o1 >= 0.f) ? o1 : aP * o1; o1 += bias3;
            const size_t o = (((size_t)n * C_ + co) << 12) + (y << 6);
            out[o + lm]      = o0;
            out[o + 32 + lm] = o1;
        }
    }
}

// ---------------- launch ----------------
extern "C" void kernel_launch(void* const* d_in, const int* in_sizes, int n_in,
                              void* d_out, int out_size, void* d_ws, size_t ws_size,
                              hipStream_t stream) {
    const float* c       = (const float*)d_in[0];
    const float* x       = (const float*)d_in[1];
    const float* emb     = (const float*)d_in[2];
    const float* gn1_g   = (const float*)d_in[3];
    const float* gn1_b   = (const float*)d_in[4];
    const float* conv1_w = (const float*)d_in[5];
    const float* conv1_b = (const float*)d_in[6];
    const float* emb_w   = (const float*)d_in[7];
    const float* emb_b   = (const float*)d_in[8];
    const float* gn2_g   = (const float*)d_in[9];
    const float* gn2_b   = (const float*)d_in[10];
    const float* conv2_w = (const float*)d_in[11];
    const float* conv2_b = (const float*)d_in[12];
    const float* m1_w    = (const float*)d_in[13];
    const float* m1_b    = (const float*)d_in[14];
    const float* bconv_w = (const float*)d_in[15];
    const float* bconv_b = (const float*)d_in[16];
    const float* bn_g    = (const float*)d_in[17];
    const float* bn_b    = (const float*)d_in[18];
    const float* m2_w    = (const float*)d_in[19];
    const float* m2_b    = (const float*)d_in[20];
    const float* prelu_a = (const float*)d_in[21];
    const float* m3_w    = (const float*)d_in[22];
    const float* m3_b    = (const float*)d_in[23];
    float* out = (float*)d_out;
    float* ws  = (float*)d_ws;

    k_fused<<<NBLK_, 256, 0, stream>>>(
        c, x, emb, gn1_g, gn1_b, conv1_w, conv1_b, emb_w, emb_b,
        gn2_g, gn2_b, conv2_w, conv2_b, m1_w, m1_b, bconv_w, bconv_b,
        bn_g, bn_b, m2_w, m2_b, prelu_a, m3_w, m3_b, out, ws);
}

// Round 4
// 242.694 us; speedup vs baseline: 1.9384x; 1.9384x over previous
//
#include <hip/hip_runtime.h>
#include <stdint.h>

// ConcatLayer_55654186221983 on MI355X (gfx950). All fp32 I/O.
// B=8, C=128, C2=256, H=W=64, EMB=512, GROUPS=32, EPS=1e-5.
// R13: back to 5 dispatches (R12 software barrier cost ~40us each - dead end).
//      vs R10: (a) stage_rows rewritten with compile-time row index (kills
//      runtime-indexed pointer array -> scratch risk, rule #20); (b) conv1
//      writes y in NHWC fp32 via LDS transpose (coalesced); conv2 stages from
//      NHWC with float4 loads + conflict-free LDS writes + hoisted GN2 affine;
//      (c) GN1 pass 2 vectorized. All math element-wise identical to R10.

#define B_   8
#define C_   128
#define C2_  256
#define HW_  4096
#define EMB_ 512
#define EPS_ 1e-5f

typedef int   v16i __attribute__((ext_vector_type(16)));
typedef float v16f __attribute__((ext_vector_type(16)));
typedef short v8s  __attribute__((ext_vector_type(8)));
typedef int   v4i  __attribute__((ext_vector_type(4)));

// LDS tile: 3 rows x 66 cols x (256 data + 16 pad) bytes
#define COLB 272
#define LDSZ (3 * 66 * COLB)
// conv1 transpose region: [64 px][132 floats] + stats
#define TSTRIDE 132

__device__ __forceinline__ float silu(float v) {
    return v * __builtin_amdgcn_rcpf(1.f + __expf(-v));
}
__device__ __forceinline__ unsigned short f2bf(float f) {
    unsigned int x = __float_as_uint(f);
    return (unsigned short)((x + 0x7FFFu + ((x >> 16) & 1u)) >> 16);  // RNE
}
__device__ __forceinline__ int8_t sgn8(float v) {
    return (v > 0.f) ? (int8_t)1 : ((v < 0.f) ? (int8_t)(-1) : (int8_t)0);
}

// ---- LDS row staging, compile-time row index (no runtime-indexed array) ----
__device__ __forceinline__ void stage_one(char* lds, int r, const char* src) {
    const int tid = threadIdx.x;
#pragma unroll
    for (int it = 0; it < 4; ++it) {
        int idx = it * 256 + tid;           // 0..1023
        int x = idx >> 4, o = idx & 15;
        char* dst = lds + (r * 66 + x + 1) * COLB + o * 16;
        if (src) *(float4*)dst = *(const float4*)(src + x * 256 + o * 16);
        else     *(float4*)dst = make_float4(0.f, 0.f, 0.f, 0.f);
    }
}
__device__ __forceinline__ void stage3(char* lds, const char* r0,
                                       const char* r1, const char* r2) {
    const int tid = threadIdx.x;
    if (tid < 96) {   // zero pad columns 0 and 65
        int r = tid / 32, q = tid & 31;
        int c = (q >> 4) ? 65 : 0, o = q & 15;
        *(float4*)(lds + (r * 66 + c) * COLB + o * 16) = make_float4(0.f, 0.f, 0.f, 0.f);
    }
    stage_one(lds, 0, r0);
    stage_one(lds, 1, r1);
    stage_one(lds, 2, r2);
}

// ---- merged prep + embedding + GN1 (1152 blocks) ----
__global__ __launch_bounds__(256) void k_prep(
    const float* __restrict__ w, int8_t* __restrict__ sgn,
    float* __restrict__ alpha, float* __restrict__ bnS, float* __restrict__ bnQ,
    float* __restrict__ gnS, float* __restrict__ gnQ,
    const float* __restrict__ w1, const float* __restrict__ w2,
    unsigned short* __restrict__ Wc1, unsigned short* __restrict__ Wc2,
    const float* __restrict__ emb,
    const float* __restrict__ ew, const float* __restrict__ ebb,
    const float* __restrict__ m1w, const float* __restrict__ m1b,
    const float* __restrict__ m2w, const float* __restrict__ m2b,
    const float* __restrict__ m3w, const float* __restrict__ m3b,
    float* __restrict__ eo, float* __restrict__ b1,
    float* __restrict__ b2, float* __restrict__ b3,
    const float* __restrict__ gin, const float* __restrict__ g1w,
    const float* __restrict__ g1b, unsigned short* __restrict__ act1) {
    __shared__ float red[256];
    const int blk = blockIdx.x, tid = threadIdx.x;
    if (blk < 128) {
        const int o = blk;
        if (o == 0 && tid < 128) { bnS[tid] = 0.f; bnQ[tid] = 0.f; }
        if (o == 1) { gnS[tid] = 0.f; }
        if (o == 2) { gnQ[tid] = 0.f; }
        const float* wr = w + (size_t)o * (C2_ * 9);
        float s = 0.f;
        for (int i = tid; i < C2_ * 9; i += 256) s += fabsf(wr[i]);
        red[tid] = s;
        __syncthreads();
        for (int st = 128; st > 0; st >>= 1) {
            if (tid < st) red[tid] += red[tid + st];
            __syncthreads();
        }
        if (tid == 0) alpha[o] = red[0] / (float)(C2_ * 9);
        for (int kk = 0; kk < 9; ++kk) {
            float v = wr[tid * 9 + kk];   // tid == ci
            sgn[((size_t)(kk * 16 + (tid >> 4)) * C_ + o) * 16 + (tid & 15)] = sgn8(v);
        }
    } else if (blk < 704) {
        int i = (blk - 128) * 256 + tid;
        int co = i / (C_ * 9);
        int rem = i - co * (C_ * 9);
        int ci = rem / 9, kk = rem - ci * 9;
        size_t d = ((size_t)(kk * 16 + (ci >> 3)) * C_ + co) * 8 + (ci & 7);
        Wc1[d] = f2bf(w1[i]);
        Wc2[d] = f2bf(w2[i]);
    } else if (blk < 896) {
        const int o = (blk - 704) * 4 + (tid >> 6);   // 0..767
        const int l = tid & 63;
        const float* wv;
        float bias;
        float* dst;
        int dstride;
        if (o < 256)      { wv = ew  + (size_t)o * EMB_;              bias = ebb[o];    dst = eo + o;  dstride = 256; }
        else if (o < 512) { int r = o - 256; wv = m1w + (size_t)r * EMB_; bias = m1b[r]; dst = b1 + r; dstride = 256; }
        else if (o < 640) { int r = o - 512; wv = m2w + (size_t)r * EMB_; bias = m2b[r]; dst = b2 + r; dstride = 128; }
        else              { int r = o - 640; wv = m3w + (size_t)r * EMB_; bias = m3b[r]; dst = b3 + r; dstride = 128; }
        const float4 wa = *(const float4*)(wv + 8 * l);
        const float4 wb = *(const float4*)(wv + 8 * l + 4);
#pragma unroll
        for (int b = 0; b < B_; ++b) {
            const float* s = emb + b * EMB_ + 8 * l;
            float4 sa = *(const float4*)(s);
            float4 sb = *(const float4*)(s + 4);
            float p = wa.x * silu(sa.x) + wa.y * silu(sa.y) + wa.z * silu(sa.z) + wa.w * silu(sa.w) +
                      wb.x * silu(sb.x) + wb.y * silu(sb.y) + wb.z * silu(sb.z) + wb.w * silu(sb.w);
#pragma unroll
            for (int off = 32; off > 0; off >>= 1) p += __shfl_down(p, off, 64);
            if (l == 0) dst[b * dstride] = bias + p;
        }
    } else {
        // GN1: one block per (n,grp), shfl reduction, vectorized both passes
        const int bb = blk - 896;
        const int n = bb >> 5, grp = bb & 31;
        const size_t base = ((size_t)(n * C_ + grp * 4)) << 12;
        float sum = 0.f, sq = 0.f;
        const float4* in4 = (const float4*)(gin + base);
        for (int i = tid; i < 4096; i += 256) {
            float4 v = in4[i];
            sum += v.x + v.y + v.z + v.w;
            sq += v.x * v.x + v.y * v.y + v.z * v.z + v.w * v.w;
        }
#pragma unroll
        for (int off = 32; off > 0; off >>= 1) {
            sum += __shfl_xor(sum, off, 64);
            sq  += __shfl_xor(sq, off, 64);
        }
        if ((tid & 63) == 0) { red[tid >> 6] = sum; red[8 + (tid >> 6)] = sq; }
        __syncthreads();
        sum = red[0] + red[1] + red[2] + red[3];
        sq  = red[8] + red[9] + red[10] + red[11];
        const float mu = sum * (1.f / 16384.f);
        const float rstd = rsqrtf(sq * (1.f / 16384.f) - mu * mu + EPS_);
        float gg[4], bb4[4];
#pragma unroll
        for (int j = 0; j < 4; ++j) { gg[j] = g1w[grp * 4 + j]; bb4[j] = g1b[grp * 4 + j]; }
        union F4 { float4 v; float f[4]; };
        for (int i = tid; i < 1024; i += 256) {
            const int hw = 4 * i;
            F4 vj[4];
#pragma unroll
            for (int j = 0; j < 4; ++j)
                vj[j].v = *(const float4*)(gin + base + ((size_t)j << 12) + hw);
#pragma unroll
            for (int e = 0; e < 4; ++e) {
                union { unsigned short u[4]; uint2 v; } pk;
#pragma unroll
                for (int j = 0; j < 4; ++j)
                    pk.u[j] = f2bf(silu((vj[j].f[e] - mu) * rstd * gg[j] + bb4[j]));
                *(uint2*)(act1 + ((size_t)(n * HW_ + hw + e)) * C_ + grp * 4) = pk.v;
            }
        }
    }
}

// ---- conv1: bf16 MFMA + fused GN2 stats; writes y in NHWC fp32 ----
__global__ __launch_bounds__(256) void k_conv1(const unsigned short* __restrict__ act,
                                               const unsigned short* __restrict__ Wc,
                                               const float* __restrict__ bias,
                                               float* __restrict__ outN,   // NHWC fp32
                                               float* __restrict__ gnS,
                                               float* __restrict__ gnQ) {
    __shared__ __align__(16) char lds[LDSZ];
    const int y = blockIdx.x;
    const int n = blockIdx.y;
    const char* base = (const char*)(act + ((size_t)n * 64) * 64 * C_);
    stage3(lds,
           (y > 0)  ? base + (size_t)(y - 1) * 16384 : nullptr,
           base + (size_t)y * 16384,
           (y < 63) ? base + (size_t)(y + 1) * 16384 : nullptr);
    __syncthreads();

    const int w = threadIdx.x >> 6;
    const int l = threadIdx.x & 63;
    const int lm = l & 31;
    const int lh = l >> 5;

    v16f acc0, acc1;
#pragma unroll
    for (int i = 0; i < 16; ++i) { acc0[i] = 0.f; acc1[i] = 0.f; }

#pragma unroll
    for (int kk = 0; kk < 9; ++kk) {
        const int r = kk / 3, dx = kk % 3 - 1;
        const char* col0 = lds + (r * 66 + lm + 1 + dx) * COLB + 16 * lh;
        const char* col1 = col0 + 32 * COLB;
        const unsigned short* wbase = Wc + (size_t)(kk * 16 + lh) * C_ * 8 + (32 * w + lm) * 8;
#pragma unroll
        for (int cb = 0; cb < 8; ++cb) {
            v8s a = *(const v8s*)(wbase + (size_t)(2 * cb) * C_ * 8);
            v8s b0 = *(const v8s*)(col0 + 32 * cb);
            v8s b1 = *(const v8s*)(col1 + 32 * cb);
            acc0 = __builtin_amdgcn_mfma_f32_32x32x16_bf16(a, b0, acc0, 0, 0, 0);
            acc1 = __builtin_amdgcn_mfma_f32_32x32x16_bf16(a, b1, acc1, 0, 0, 0);
        }
    }
    float sv0[16], sv1[16], pr[16], qr[16];
#pragma unroll
    for (int r = 0; r < 16; ++r) {
        const int row = (r & 3) + 8 * (r >> 2) + 4 * lh;
        const int co = 32 * w + row;
        const float bv = bias[co];
        float v0 = acc0[r] + bv, v1 = acc1[r] + bv;
        sv0[r] = v0;
        sv1[r] = v1;
        pr[r] = v0 + v1;
        qr[r] = v0 * v0 + v1 * v1;
    }
    __syncthreads();   // staging LDS fully consumed; reuse for transpose+stats
    float* ldsT = (float*)lds;                       // [64][TSTRIDE]
    float* ldsS = (float*)(lds + 64 * TSTRIDE * 4);  // 128 floats
    float* ldsQ = ldsS + 128;
#pragma unroll
    for (int r = 0; r < 16; ++r) {
        const int row = (r & 3) + 8 * (r >> 2) + 4 * lh;
        const int co = 32 * w + row;
        ldsT[lm * TSTRIDE + co] = sv0[r];
        ldsT[(32 + lm) * TSTRIDE + co] = sv1[r];
        float p = pr[r], q = qr[r];
#pragma unroll
        for (int m = 16; m > 0; m >>= 1) {
            p += __shfl_xor(p, m, 64);
            q += __shfl_xor(q, m, 64);
        }
        if (lm == 0) { ldsS[co] = p; ldsQ[co] = q; }
    }
    __syncthreads();
    if (threadIdx.x < 32) {
        const int g = threadIdx.x;
        float p = ldsS[4 * g] + ldsS[4 * g + 1] + ldsS[4 * g + 2] + ldsS[4 * g + 3];
        float q = ldsQ[4 * g] + ldsQ[4 * g + 1] + ldsQ[4 * g + 2] + ldsQ[4 * g + 3];
        atomicAdd(&gnS[n * 32 + g], p);
        atomicAdd(&gnQ[n * 32 + g], q);
    }
    // coalesced NHWC store: y[(n*HW + y*64 + px)*128 + ch]
    const int q4 = threadIdx.x & 31;
    float* orow = outN + (((size_t)(n * HW_) + (y << 6)) << 7);
#pragma unroll
    for (int it = 0; it < 8; ++it) {
        const int px = it * 8 + (threadIdx.x >> 5);
        *(float4*)(orow + ((size_t)px << 7) + 4 * q4) =
            *(const float4*)(ldsT + px * TSTRIDE + 4 * q4);
    }
}

// ---- conv2: stages GN2+FiLM+SiLU from NHWC fp32 y; sign + pool epilogue ----
__global__ __launch_bounds__(256) void k_conv2(const float* __restrict__ yin,  // NHWC
                                               const unsigned short* __restrict__ Wc,
                                               const float* __restrict__ bias,
                                               const float* __restrict__ res,
                                               const float* __restrict__ xin,
                                               const float* __restrict__ b1v,
                                               const float* __restrict__ eo,
                                               const float* __restrict__ g2,
                                               const float* __restrict__ bt2,
                                               const float* __restrict__ gnS,
                                               const float* __restrict__ gnQ,
                                               float* __restrict__ poolC2,
                                               int8_t* __restrict__ S) {
    __shared__ __align__(16) char lds[LDSZ];
    __shared__ float ldsA[128], ldsB[128];
    const int y = blockIdx.x;
    const int n = blockIdx.y;
    const int tid = threadIdx.x;

    if (tid < 128) {
        const int ch = tid, grp = tid >> 2;
        const float mu = gnS[n * 32 + grp] * (1.f / 16384.f);
        const float var = gnQ[n * 32 + grp] * (1.f / 16384.f) - mu * mu;
        const float rstd = rsqrtf(var + EPS_);
        const float gg = g2[ch] * rstd;
        const float sc = 1.f + eo[n * 256 + ch];
        ldsA[ch] = gg * sc;
        ldsB[ch] = (bt2[ch] - mu * gg) * sc + eo[n * 256 + 128 + ch];
    }
    if (tid < 96) {   // zero pad columns 0 and 65
        int r = tid / 32, q = tid & 31;
        int cpad = (q >> 4) ? 65 : 0, o = q & 15;
        *(float4*)(lds + (r * 66 + cpad) * COLB + o * 16) = make_float4(0.f, 0.f, 0.f, 0.f);
    }
    __syncthreads();

    // staging: per thread a fixed channel-quad qc; affine coeffs hoisted
    const int qc = tid & 31;
    float A0 = ldsA[4 * qc], A1 = ldsA[4 * qc + 1], A2 = ldsA[4 * qc + 2], A3 = ldsA[4 * qc + 3];
    float B0 = ldsB[4 * qc], B1 = ldsB[4 * qc + 1], B2 = ldsB[4 * qc + 2], B3 = ldsB[4 * qc + 3];
#pragma unroll
    for (int r = 0; r < 3; ++r) {
        const int yy = y - 1 + r;
        const float* ysrc = yin + (((size_t)(n * HW_) + yy * 64) << 7);
        const bool ok = (yy >= 0 && yy < 64);
#pragma unroll
        for (int it = 0; it < 8; ++it) {
            const int px = it * 8 + (tid >> 5);
            char* dst = lds + (r * 66 + px + 1) * COLB + qc * 8;
            if (ok) {
                float4 v = *(const float4*)(ysrc + ((size_t)px << 7) + 4 * qc);
                union { unsigned short u[4]; uint2 q; } pk;
                pk.u[0] = f2bf(silu(v.x * A0 + B0));
                pk.u[1] = f2bf(silu(v.y * A1 + B1));
                pk.u[2] = f2bf(silu(v.z * A2 + B2));
                pk.u[3] = f2bf(silu(v.w * A3 + B3));
                *(uint2*)dst = pk.q;
            } else {
                *(uint2*)dst = make_uint2(0u, 0u);
            }
        }
    }
    __syncthreads();

    const int w = tid >> 6;
    const int l = tid & 63;
    const int lm = l & 31;
    const int lh = l >> 5;

    v16f acc0, acc1;
#pragma unroll
    for (int i = 0; i < 16; ++i) { acc0[i] = 0.f; acc1[i] = 0.f; }

#pragma unroll
    for (int kk = 0; kk < 9; ++kk) {
        const int r = kk / 3, dx = kk % 3 - 1;
        const char* col0 = lds + (r * 66 + lm + 1 + dx) * COLB + 16 * lh;
        const char* col1 = col0 + 32 * COLB;
        const unsigned short* wbase = Wc + (size_t)(kk * 16 + lh) * C_ * 8 + (32 * w + lm) * 8;
#pragma unroll
        for (int cb = 0; cb < 8; ++cb) {
            v8s a = *(const v8s*)(wbase + (size_t)(2 * cb) * C_ * 8);
            v8s b0 = *(const v8s*)(col0 + 32 * cb);
            v8s b1 = *(const v8s*)(col1 + 32 * cb);
            acc0 = __builtin_amdgcn_mfma_f32_32x32x16_bf16(a, b0, acc0, 0, 0, 0);
            acc1 = __builtin_amdgcn_mfma_f32_32x32x16_bf16(a, b1, acc1, 0, 0, 0);
        }
    }
    float c2v0[16], c2v1[16];
#pragma unroll
    for (int r = 0; r < 16; ++r) {
        const int row = (r & 3) + 8 * (r >> 2) + 4 * lh;
        const int co = 32 * w + row;
        const float bv = bias[co];
        const size_t o = (((size_t)n * C_ + co) << 12) + (y << 6);
        c2v0[r] = acc0[r] + bv + res[o + lm];
        c2v1[r] = acc1[r] + bv + res[o + 32 + lm];
    }
    // pooled c2-half (channel-pair means), in-register
#pragma unroll
    for (int q = 0; q < 4; ++q) {
        const int pc = 16 * w + 4 * q + 2 * lh;   // pooled channel (0..63)
        const size_t po = (((size_t)n * 64 + pc) << 12) + (y << 6);
        poolC2[po + lm]             = 0.5f * (c2v0[4 * q] + c2v0[4 * q + 1]);
        poolC2[po + 32 + lm]        = 0.5f * (c2v1[4 * q] + c2v1[4 * q + 1]);
        poolC2[po + 4096 + lm]      = 0.5f * (c2v0[4 * q + 2] + c2v0[4 * q + 3]);
        poolC2[po + 4096 + 32 + lm] = 0.5f * (c2v1[4 * q + 2] + c2v1[4 * q + 3]);
    }

    // fused sign: build S row [64 px][256 ch] bytes in LDS, then store
    __syncthreads();
#pragma unroll
    for (int q = 0; q < 4; ++q) {
        const int co0 = 32 * w + 8 * q + 4 * lh;
        const float b0 = b1v[n * 256 + 128 + co0];
        const float b1b = b1v[n * 256 + 128 + co0 + 1];
        const float b2b = b1v[n * 256 + 128 + co0 + 2];
        const float b3b = b1v[n * 256 + 128 + co0 + 3];
        union { int8_t b[4]; int u; } p0, p1;
        p0.b[0] = sgn8(c2v0[4 * q] + b0);      p1.b[0] = sgn8(c2v1[4 * q] + b0);
        p0.b[1] = sgn8(c2v0[4 * q + 1] + b1b); p1.b[1] = sgn8(c2v1[4 * q + 1] + b1b);
        p0.b[2] = sgn8(c2v0[4 * q + 2] + b2b); p1.b[2] = sgn8(c2v1[4 * q + 2] + b2b);
        p0.b[3] = sgn8(c2v0[4 * q + 3] + b3b); p1.b[3] = sgn8(c2v1[4 * q + 3] + b3b);
        *(int*)(lds + lm * COLB + 128 + co0) = p0.u;
        *(int*)(lds + (32 + lm) * COLB + 128 + co0) = p1.u;
    }
#pragma unroll
    for (int u = 0; u < 8; ++u) {
        int idx = u * 256 + tid;
        int ch = idx >> 4, seg = idx & 15;
        float4 v = *(const float4*)(xin + (((size_t)(n * C_ + ch)) << 12) + (y << 6) + 4 * seg);
        const float bv = b1v[n * 256 + ch];
        lds[(4 * seg) * COLB + ch]     = sgn8(v.x + bv);
        lds[(4 * seg + 1) * COLB + ch] = sgn8(v.y + bv);
        lds[(4 * seg + 2) * COLB + ch] = sgn8(v.z + bv);
        lds[(4 * seg + 3) * COLB + ch] = sgn8(v.w + bv);
    }
    __syncthreads();
    int8_t* Srow = S + ((size_t)(n * HW_) + (y << 6)) * C2_;
#pragma unroll
    for (int u = 0; u < 4; ++u) {
        int idx = u * 256 + tid;
        int px = idx >> 4, c16 = idx & 15;
        *(int4*)(Srow + (size_t)px * C2_ + 16 * c16) = *(const int4*)(lds + px * COLB + 16 * c16);
    }
}

// ---- binary conv: i8 K=32 MFMA + fused BN stats ----
__global__ __launch_bounds__(256) void k_bconv(const int8_t* __restrict__ S,
                                               const int8_t* __restrict__ Wk,
                                               const float* __restrict__ alpha,
                                               const float* __restrict__ bias,
                                               float* __restrict__ out,
                                               float* __restrict__ bnS,
                                               float* __restrict__ bnQ) {
    __shared__ __align__(16) char lds[LDSZ];
    const int y = blockIdx.x;
    const int n = blockIdx.y;
    const char* base = (const char*)(S + ((size_t)n * 64) * 64 * C2_);
    stage3(lds,
           (y > 0)  ? base + (size_t)(y - 1) * 16384 : nullptr,
           base + (size_t)y * 16384,
           (y < 63) ? base + (size_t)(y + 1) * 16384 : nullptr);
    __syncthreads();

    const int w = threadIdx.x >> 6;
    const int l = threadIdx.x & 63;
    const int lm = l & 31;
    const int lh = l >> 5;

    v16i acc0, acc1;
#pragma unroll
    for (int i = 0; i < 16; ++i) { acc0[i] = 0; acc1[i] = 0; }

#pragma unroll
    for (int kk = 0; kk < 9; ++kk) {
        const int r = kk / 3, dx = kk % 3 - 1;
        const char* col0 = lds + (r * 66 + lm + 1 + dx) * COLB + 16 * lh;
        const char* col1 = col0 + 32 * COLB;
        const int8_t* wbase = Wk + (size_t)(kk * 16 + lh) * C_ * 16 + (32 * w + lm) * 16;
#pragma unroll
        for (int s = 0; s < 8; ++s) {
            v4i a = *(const v4i*)(wbase + (size_t)(2 * s) * C_ * 16);
            v4i b0 = *(const v4i*)(col0 + 32 * s);
            v4i b1 = *(const v4i*)(col1 + 32 * s);
            acc0 = __builtin_amdgcn_mfma_i32_32x32x32_i8(a, b0, acc0, 0, 0, 0);
            acc1 = __builtin_amdgcn_mfma_i32_32x32x32_i8(a, b1, acc1, 0, 0, 0);
        }
    }

    float pr[16], qr[16];
#pragma unroll
    for (int r = 0; r < 16; ++r) {
        const int row = (r & 3) + 8 * (r >> 2) + 4 * lh;
        const int co = 32 * w + row;
        const float av = alpha[co], bv = bias[co];
        const size_t o = (((size_t)n * C_ + co) << 12) + (y << 6);
        float v0 = av * (float)acc0[r] + bv;
        float v1 = av * (float)acc1[r] + bv;
        out[o + lm]      = v0;
        out[o + 32 + lm] = v1;
        pr[r] = v0 + v1;
        qr[r] = v0 * v0 + v1 * v1;
    }
    __syncthreads();
    float* ldsS = (float*)lds;
    float* ldsQ = (float*)lds + 128;
#pragma unroll
    for (int r = 0; r < 16; ++r) {
        float p = pr[r], q = qr[r];
#pragma unroll
        for (int m = 16; m > 0; m >>= 1) {
            p += __shfl_xor(p, m, 64);
            q += __shfl_xor(q, m, 64);
        }
        if (lm == 0) {
            const int row = (r & 3) + 8 * (r >> 2) + 4 * lh;
            const int co = 32 * w + row;
            ldsS[co] = p;
            ldsQ[co] = q;
        }
    }
    __syncthreads();
    if (threadIdx.x < 128) {
        atomicAdd(&bnS[threadIdx.x], ldsS[threadIdx.x]);
        atomicAdd(&bnQ[threadIdx.x], ldsQ[threadIdx.x]);
    }
}

// ---- final epilogue, float4 ----
__global__ __launch_bounds__(256) void k_final(const float* __restrict__ y3,
                                               const float* __restrict__ x,
                                               const float* __restrict__ poolC2,
                                               const float* __restrict__ bnS,
                                               const float* __restrict__ bnQ,
                                               const float* __restrict__ bng,
                                               const float* __restrict__ bnb,
                                               const float* __restrict__ b2v,
                                               const float* __restrict__ pa,
                                               const float* __restrict__ b3v,
                                               float* __restrict__ out) {
    const int idx4 = blockIdx.x * 256 + threadIdx.x;   // < 1,048,576
    const int hw = (idx4 & 1023) * 4;
    const int cb = idx4 >> 10;
    const int co = cb & 127;
    const int n = cb >> 7;
    const float mu = bnS[co] * (1.f / 32768.f);
    const float var = bnQ[co] * (1.f / 32768.f) - mu * mu;
    const float rstd = rsqrtf(var + EPS_);
    const float gm = rstd * bng[co];
    const float bt = bnb[co] - mu * gm;
    const size_t obase = (((size_t)(n * C_ + co)) << 12) + hw;
    float4 v = *(const float4*)(y3 + obase);
    v.x = v.x * gm + bt; v.y = v.y * gm + bt; v.z = v.z * gm + bt; v.w = v.w * gm + bt;

    float4 pv;
    if (co < 64) {
        const int ch0 = 2 * co;
        float4 pA = *(const float4*)(x + (((size_t)(n * C_ + ch0)) << 12) + hw);
        float4 pB = *(const float4*)(x + (((size_t)(n * C_ + ch0 + 1)) << 12) + hw);
        pv.x = 0.5f * (pA.x + pB.x); pv.y = 0.5f * (pA.y + pB.y);
        pv.z = 0.5f * (pA.z + pB.z); pv.w = 0.5f * (pA.w + pB.w);
    } else {
        pv = *(const float4*)(poolC2 + (((size_t)(n * 64 + co - 64)) << 12) + hw);
    }
    const float bias2 = b2v[n * 128 + co];
    const float aP = pa[co];
    const float bias3 = b3v[n * 128 + co];
    float4 r;
    float t;
    t = v.x + pv.x + bias2; t = (t >= 0.f) ? t : aP * t; r.x = t + bias3;
    t = v.y + pv.y + bias2; t = (t >= 0.f) ? t : aP * t; r.y = t + bias3;
    t = v.z + pv.z + bias2; t = (t >= 0.f) ? t : aP * t; r.z = t + bias3;
    t = v.w + pv.w + bias2; t = (t >= 0.f) ? t : aP * t; r.w = t + bias3;
    *(float4*)(out + obase) = r;
}

// ---------------- launch ----------------
extern "C" void kernel_launch(void* const* d_in, const int* in_sizes, int n_in,
                              void* d_out, int out_size, void* d_ws, size_t ws_size,
                              hipStream_t stream) {
    const float* c       = (const float*)d_in[0];
    const float* x       = (const float*)d_in[1];
    const float* emb     = (const float*)d_in[2];
    const float* gn1_g   = (const float*)d_in[3];
    const float* gn1_b   = (const float*)d_in[4];
    const float* conv1_w = (const float*)d_in[5];
    const float* conv1_b = (const float*)d_in[6];
    const float* emb_w   = (const float*)d_in[7];
    const float* emb_b   = (const float*)d_in[8];
    const float* gn2_g   = (const float*)d_in[9];
    const float* gn2_b   = (const float*)d_in[10];
    const float* conv2_w = (const float*)d_in[11];
    const float* conv2_b = (const float*)d_in[12];
    const float* m1_w    = (const float*)d_in[13];
    const float* m1_b    = (const float*)d_in[14];
    const float* bconv_w = (const float*)d_in[15];
    const float* bconv_b = (const float*)d_in[16];
    const float* bn_g    = (const float*)d_in[17];
    const float* bn_b    = (const float*)d_in[18];
    const float* m2_w    = (const float*)d_in[19];
    const float* m2_b    = (const float*)d_in[20];
    const float* prelu_a = (const float*)d_in[21];
    const float* m3_w    = (const float*)d_in[22];
    const float* m3_b    = (const float*)d_in[23];
    float* out = (float*)d_out;

    float* ws = (float*)d_ws;
    const size_t NCHW = (size_t)B_ * C_ * HW_;       // 4,194,304
    float*  poolC2 = ws;
    float*  y_buf = ws + NCHW;          // conv1 NHWC fp32, later bconv NCHW out
    unsigned short* actA = (unsigned short*)(ws + 2 * NCHW);   // bf16 NHWC
    int8_t* S     = (int8_t*)(ws + 2 * NCHW);                  // aliases actA
    int8_t* sgn   = (int8_t*)(ws + 2 * NCHW + NCHW / 2);
    unsigned short* Wc1 = (unsigned short*)(ws + 2 * NCHW + NCHW / 2 + 73728);
    unsigned short* Wc2 = Wc1 + C_ * C_ * 9;
    float*  alpha = ws + 2 * NCHW + NCHW / 2 + 73728 + 2 * 73728;
    float*  eo    = alpha + 128;
    float*  b1v   = eo + B_ * 256;
    float*  b2v   = b1v + B_ * 256;
    float*  b3v   = b2v + B_ * 128;
    float*  bnS   = b3v + B_ * 128;
    float*  bnQ   = bnS + 128;
    float*  gnS   = bnQ + 128;   // 256
    float*  gnQ   = gnS + 256;   // 256

    k_prep<<<1152, 256, 0, stream>>>(bconv_w, sgn, alpha, bnS, bnQ, gnS, gnQ,
                                     conv1_w, conv2_w, Wc1, Wc2,
                                     emb, emb_w, emb_b, m1_w, m1_b, m2_w, m2_b,
                                     m3_w, m3_b, eo, b1v, b2v, b3v,
                                     c, gn1_g, gn1_b, actA);
    k_conv1<<<dim3(64, B_), 256, 0, stream>>>(actA, Wc1, conv1_b, y_buf, gnS, gnQ);
    k_conv2<<<dim3(64, B_), 256, 0, stream>>>(y_buf, Wc2, conv2_b, c, x, b1v, eo,
                                              gn2_g, gn2_b, gnS, gnQ, poolC2, S);
    k_bconv<<<dim3(64, B_), 256, 0, stream>>>(S, sgn, alpha, bconv_b, y_buf, bnS, bnQ);
    k_final<<<NCHW / 1024, 256, 0, stream>>>(y_buf, x, poolC2, bnS, bnQ, bn_g, bn_b,
                                             b2v, prelu_a, b3v, out);
}

// Round 5
// 219.296 us; speedup vs baseline: 2.1452x; 1.1067x over previous
//
#include <hip/hip_runtime.h>
#include <stdint.h>

// ConcatLayer_55654186221983 on MI355X (gfx950). All fp32 I/O.
// B=8, C=128, C2=256, H=W=64, EMB=512, GROUPS=32, EPS=1e-5.
// R14: conv kernels -> 512-thr / 8-wave blocks: waves = (och-group 0..3) x
//      (px-half 0..1) sharing ONE staged LDS tile. 16 waves/CU (was 8) for
//      latency hiding; weight/staging traffic unchanged. GN1 folded into
//      conv1 staging (stats-only in prep; actA buffer eliminated).

#define B_   8
#define C_   128
#define C2_  256
#define HW_  4096
#define EMB_ 512
#define EPS_ 1e-5f

typedef int   v16i __attribute__((ext_vector_type(16)));
typedef float v16f __attribute__((ext_vector_type(16)));
typedef short v8s  __attribute__((ext_vector_type(8)));
typedef int   v4i  __attribute__((ext_vector_type(4)));

// LDS tile: 3 rows x 66 cols x (256 data + 16 pad) bytes
#define COLB 272
#define LDSZ (3 * 66 * COLB)
#define TSTRIDE 132

__device__ __forceinline__ float silu(float v) {
    return v * __builtin_amdgcn_rcpf(1.f + __expf(-v));
}
__device__ __forceinline__ unsigned short f2bf(float f) {
    unsigned int x = __float_as_uint(f);
    return (unsigned short)((x + 0x7FFFu + ((x >> 16) & 1u)) >> 16);  // RNE
}
__device__ __forceinline__ int8_t sgn8(float v) {
    return (v > 0.f) ? (int8_t)1 : ((v < 0.f) ? (int8_t)(-1) : (int8_t)0);
}

// ---- merged prep + embedding + GN1-stats (1152 blocks x 256) ----
__global__ __launch_bounds__(256) void k_prep(
    const float* __restrict__ w, int8_t* __restrict__ sgn,
    float* __restrict__ alpha, float* __restrict__ bnS, float* __restrict__ bnQ,
    float* __restrict__ gnS, float* __restrict__ gnQ,
    const float* __restrict__ w1, const float* __restrict__ w2,
    unsigned short* __restrict__ Wc1, unsigned short* __restrict__ Wc2,
    const float* __restrict__ emb,
    const float* __restrict__ ew, const float* __restrict__ ebb,
    const float* __restrict__ m1w, const float* __restrict__ m1b,
    const float* __restrict__ m2w, const float* __restrict__ m2b,
    const float* __restrict__ m3w, const float* __restrict__ m3b,
    float* __restrict__ eo, float* __restrict__ b1,
    float* __restrict__ b2, float* __restrict__ b3,
    const float* __restrict__ gin,
    float* __restrict__ g1S, float* __restrict__ g1Q) {
    __shared__ float red[256];
    const int blk = blockIdx.x, tid = threadIdx.x;
    if (blk < 128) {
        const int o = blk;
        if (o == 0 && tid < 128) { bnS[tid] = 0.f; bnQ[tid] = 0.f; }
        if (o == 1) { gnS[tid] = 0.f; }
        if (o == 2) { gnQ[tid] = 0.f; }
        const float* wr = w + (size_t)o * (C2_ * 9);
        float s = 0.f;
        for (int i = tid; i < C2_ * 9; i += 256) s += fabsf(wr[i]);
        red[tid] = s;
        __syncthreads();
        for (int st = 128; st > 0; st >>= 1) {
            if (tid < st) red[tid] += red[tid + st];
            __syncthreads();
        }
        if (tid == 0) alpha[o] = red[0] / (float)(C2_ * 9);
        for (int kk = 0; kk < 9; ++kk) {
            float v = wr[tid * 9 + kk];   // tid == ci
            sgn[((size_t)(kk * 16 + (tid >> 4)) * C_ + o) * 16 + (tid & 15)] = sgn8(v);
        }
    } else if (blk < 704) {
        int i = (blk - 128) * 256 + tid;
        int co = i / (C_ * 9);
        int rem = i - co * (C_ * 9);
        int ci = rem / 9, kk = rem - ci * 9;
        size_t d = ((size_t)(kk * 16 + (ci >> 3)) * C_ + co) * 8 + (ci & 7);
        Wc1[d] = f2bf(w1[i]);
        Wc2[d] = f2bf(w2[i]);
    } else if (blk < 896) {
        const int o = (blk - 704) * 4 + (tid >> 6);   // 0..767
        const int l = tid & 63;
        const float* wv;
        float bias;
        float* dst;
        int dstride;
        if (o < 256)      { wv = ew  + (size_t)o * EMB_;              bias = ebb[o];    dst = eo + o;  dstride = 256; }
        else if (o < 512) { int r = o - 256; wv = m1w + (size_t)r * EMB_; bias = m1b[r]; dst = b1 + r; dstride = 256; }
        else if (o < 640) { int r = o - 512; wv = m2w + (size_t)r * EMB_; bias = m2b[r]; dst = b2 + r; dstride = 128; }
        else              { int r = o - 640; wv = m3w + (size_t)r * EMB_; bias = m3b[r]; dst = b3 + r; dstride = 128; }
        const float4 wa = *(const float4*)(wv + 8 * l);
        const float4 wb = *(const float4*)(wv + 8 * l + 4);
#pragma unroll
        for (int b = 0; b < B_; ++b) {
            const float* s = emb + b * EMB_ + 8 * l;
            float4 sa = *(const float4*)(s);
            float4 sb = *(const float4*)(s + 4);
            float p = wa.x * silu(sa.x) + wa.y * silu(sa.y) + wa.z * silu(sa.z) + wa.w * silu(sa.w) +
                      wb.x * silu(sb.x) + wb.y * silu(sb.y) + wb.z * silu(sb.z) + wb.w * silu(sb.w);
#pragma unroll
            for (int off = 32; off > 0; off >>= 1) p += __shfl_down(p, off, 64);
            if (l == 0) dst[b * dstride] = bias + p;
        }
    } else {
        // GN1 stats only (apply folded into conv1 staging)
        const int bb = blk - 896;
        const int n = bb >> 5, grp = bb & 31;
        const size_t base = ((size_t)(n * C_ + grp * 4)) << 12;
        float sum = 0.f, sq = 0.f;
        const float4* in4 = (const float4*)(gin + base);
        for (int i = tid; i < 4096; i += 256) {
            float4 v = in4[i];
            sum += v.x + v.y + v.z + v.w;
            sq += v.x * v.x + v.y * v.y + v.z * v.z + v.w * v.w;
        }
#pragma unroll
        for (int off = 32; off > 0; off >>= 1) {
            sum += __shfl_xor(sum, off, 64);
            sq  += __shfl_xor(sq, off, 64);
        }
        if ((tid & 63) == 0) { red[tid >> 6] = sum; red[8 + (tid >> 6)] = sq; }
        __syncthreads();
        if (tid == 0) {
            g1S[n * 32 + grp] = red[0] + red[1] + red[2] + red[3];
            g1Q[n * 32 + grp] = red[8] + red[9] + red[10] + red[11];
        }
    }
}

// ---- conv1: stages GN1+SiLU+bf16 from NCHW c; bf16 MFMA; GN2 stats;
//      writes y NHWC fp32. 512 thr, wave = (og, ph). ----
__global__ __launch_bounds__(512, 4) void k_conv1(
    const float* __restrict__ cin,
    const unsigned short* __restrict__ Wc,
    const float* __restrict__ bias,
    const float* __restrict__ g1w, const float* __restrict__ g1b,
    const float* __restrict__ g1S, const float* __restrict__ g1Q,
    float* __restrict__ outN,
    float* __restrict__ gnS, float* __restrict__ gnQ) {
    __shared__ __align__(16) char lds[LDSZ];
    __shared__ float chA[128], chB[128];
    const int y = blockIdx.x;
    const int n = blockIdx.y;
    const int tid = threadIdx.x;

    if (tid < 128) {   // GN1 per-channel affine: act = silu(v*A + B)
        const int ch = tid, grp = tid >> 2;
        const float mu = g1S[n * 32 + grp] * (1.f / 16384.f);
        const float var = g1Q[n * 32 + grp] * (1.f / 16384.f) - mu * mu;
        const float rstd = rsqrtf(var + EPS_);
        const float A = g1w[ch] * rstd;
        chA[ch] = A;
        chB[ch] = g1b[ch] - mu * A;
    }
    if (tid < 96) {   // zero pad columns 0 and 65
        int r = tid / 32, q = tid & 31;
        int c = (q >> 4) ? 65 : 0, o = q & 15;
        *(float4*)(lds + (r * 66 + c) * COLB + o * 16) = make_float4(0.f, 0.f, 0.f, 0.f);
    }
    __syncthreads();

    // staging with GN1+SiLU+bf16 transform; px = seg + 16j (4-way-ish conflicts)
#pragma unroll
    for (int u = 0; u < 12; ++u) {
        int unit = u * 512 + tid;            // 0..6143 = 3 rows x 128 ch x 16 seg
        int r = unit >> 11, rem = unit & 2047;
        int ch = rem >> 4, seg = rem & 15;
        int yy = y - 1 + r;
        char* dst = lds + (r * 66 + 1 + seg) * COLB + 2 * ch;
        if (yy >= 0 && yy < 64) {
            const float A = chA[ch], Bv = chB[ch];
            const float* src = cin + (((size_t)(n * C_ + ch)) << 12) + yy * 64 + seg;
#pragma unroll
            for (int j = 0; j < 4; ++j)
                *(unsigned short*)(dst + (16 * j) * COLB) = f2bf(silu(src[16 * j] * A + Bv));
        } else {
#pragma unroll
            for (int j = 0; j < 4; ++j)
                *(unsigned short*)(dst + (16 * j) * COLB) = 0;
        }
    }
    __syncthreads();

    const int w = tid >> 6;
    const int og = w >> 1;     // och group (32 ch)
    const int ph = w & 1;      // px half (32 px)
    const int l = tid & 63;
    const int lm = l & 31;
    const int lh = l >> 5;

    v16f acc;
#pragma unroll
    for (int i = 0; i < 16; ++i) acc[i] = 0.f;

#pragma unroll
    for (int kk = 0; kk < 9; ++kk) {
        const int r = kk / 3, dx = kk % 3 - 1;
        const char* col = lds + (r * 66 + 32 * ph + lm + 1 + dx) * COLB + 16 * lh;
        const unsigned short* wbase = Wc + (size_t)(kk * 16 + lh) * C_ * 8 + (32 * og + lm) * 8;
#pragma unroll
        for (int cb = 0; cb < 8; ++cb) {
            v8s a = *(const v8s*)(wbase + (size_t)(2 * cb) * C_ * 8);
            v8s b = *(const v8s*)(col + 32 * cb);
            acc = __builtin_amdgcn_mfma_f32_32x32x16_bf16(a, b, acc, 0, 0, 0);
        }
    }
    __syncthreads();   // staging LDS fully consumed; reuse for transpose+stats
    float* ldsT = (float*)lds;                        // [64][TSTRIDE]
    float* ldsS = (float*)(lds + 64 * TSTRIDE * 4);   // [2][128]
    float* ldsQ = ldsS + 256;                         // [2][128]
#pragma unroll
    for (int r = 0; r < 16; ++r) {
        const int row = (r & 3) + 8 * (r >> 2) + 4 * lh;
        const int co = 32 * og + row;
        float v = acc[r] + bias[co];
        ldsT[(32 * ph + lm) * TSTRIDE + co] = v;
        float p = v, q = v * v;
#pragma unroll
        for (int m = 16; m > 0; m >>= 1) {
            p += __shfl_xor(p, m, 64);
            q += __shfl_xor(q, m, 64);
        }
        if (lm == 0) { ldsS[ph * 128 + co] = p; ldsQ[ph * 128 + co] = q; }
    }
    __syncthreads();
    if (tid < 32) {
        const int g = tid;
        float p = 0.f, q = 0.f;
#pragma unroll
        for (int j = 0; j < 4; ++j) {
            p += ldsS[4 * g + j] + ldsS[128 + 4 * g + j];
            q += ldsQ[4 * g + j] + ldsQ[128 + 4 * g + j];
        }
        atomicAdd(&gnS[n * 32 + g], p);
        atomicAdd(&gnQ[n * 32 + g], q);
    }
    // coalesced NHWC store
    const int q4 = tid & 31;
    float* orow = outN + (((size_t)(n * HW_) + (y << 6)) << 7);
#pragma unroll
    for (int it = 0; it < 4; ++it) {
        const int px = it * 16 + (tid >> 5);
        *(float4*)(orow + ((size_t)px << 7) + 4 * q4) =
            *(const float4*)(ldsT + px * TSTRIDE + 4 * q4);
    }
}

// ---- conv2: stages GN2+FiLM+SiLU from NHWC fp32 y; MFMA; sign + pool ----
__global__ __launch_bounds__(512, 4) void k_conv2(
    const float* __restrict__ yin,  // NHWC
    const unsigned short* __restrict__ Wc,
    const float* __restrict__ bias,
    const float* __restrict__ res,
    const float* __restrict__ xin,
    const float* __restrict__ b1v,
    const float* __restrict__ eo,
    const float* __restrict__ g2,
    const float* __restrict__ bt2,
    const float* __restrict__ gnS,
    const float* __restrict__ gnQ,
    float* __restrict__ poolC2,
    int8_t* __restrict__ S) {
    __shared__ __align__(16) char lds[LDSZ];
    __shared__ float ldsA[128], ldsB[128];
    const int y = blockIdx.x;
    const int n = blockIdx.y;
    const int tid = threadIdx.x;

    if (tid < 128) {
        const int ch = tid, grp = tid >> 2;
        const float mu = gnS[n * 32 + grp] * (1.f / 16384.f);
        const float var = gnQ[n * 32 + grp] * (1.f / 16384.f) - mu * mu;
        const float rstd = rsqrtf(var + EPS_);
        const float gg = g2[ch] * rstd;
        const float sc = 1.f + eo[n * 256 + ch];
        ldsA[ch] = gg * sc;
        ldsB[ch] = (bt2[ch] - mu * gg) * sc + eo[n * 256 + 128 + ch];
    }
    if (tid < 96) {
        int r = tid / 32, q = tid & 31;
        int cpad = (q >> 4) ? 65 : 0, o = q & 15;
        *(float4*)(lds + (r * 66 + cpad) * COLB + o * 16) = make_float4(0.f, 0.f, 0.f, 0.f);
    }
    __syncthreads();

    // staging from NHWC: thread owns channel-quad qc; affine coeffs hoisted
    const int qc = tid & 31;
    const float A0 = ldsA[4 * qc], A1 = ldsA[4 * qc + 1], A2 = ldsA[4 * qc + 2], A3 = ldsA[4 * qc + 3];
    const float B0 = ldsB[4 * qc], B1 = ldsB[4 * qc + 1], B2 = ldsB[4 * qc + 2], B3 = ldsB[4 * qc + 3];
#pragma unroll
    for (int r = 0; r < 3; ++r) {
        const int yy = y - 1 + r;
        const float* ysrc = yin + (((size_t)(n * HW_) + yy * 64) << 7);
        const bool ok = (yy >= 0 && yy < 64);
#pragma unroll
        for (int it = 0; it < 4; ++it) {
            const int px = it * 16 + (tid >> 5);
            char* dst = lds + (r * 66 + px + 1) * COLB + qc * 8;
            if (ok) {
                float4 v = *(const float4*)(ysrc + ((size_t)px << 7) + 4 * qc);
                union { unsigned short u[4]; uint2 q; } pk;
                pk.u[0] = f2bf(silu(v.x * A0 + B0));
                pk.u[1] = f2bf(silu(v.y * A1 + B1));
                pk.u[2] = f2bf(silu(v.z * A2 + B2));
                pk.u[3] = f2bf(silu(v.w * A3 + B3));
                *(uint2*)dst = pk.q;
            } else {
                *(uint2*)dst = make_uint2(0u, 0u);
            }
        }
    }
    __syncthreads();

    const int w = tid >> 6;
    const int og = w >> 1;
    const int ph = w & 1;
    const int l = tid & 63;
    const int lm = l & 31;
    const int lh = l >> 5;

    v16f acc;
#pragma unroll
    for (int i = 0; i < 16; ++i) acc[i] = 0.f;

#pragma unroll
    for (int kk = 0; kk < 9; ++kk) {
        const int r = kk / 3, dx = kk % 3 - 1;
        const char* col = lds + (r * 66 + 32 * ph + lm + 1 + dx) * COLB + 16 * lh;
        const unsigned short* wbase = Wc + (size_t)(kk * 16 + lh) * C_ * 8 + (32 * og + lm) * 8;
#pragma unroll
        for (int cb = 0; cb < 8; ++cb) {
            v8s a = *(const v8s*)(wbase + (size_t)(2 * cb) * C_ * 8);
            v8s b = *(const v8s*)(col + 32 * cb);
            acc = __builtin_amdgcn_mfma_f32_32x32x16_bf16(a, b, acc, 0, 0, 0);
        }
    }
    float c2v[16];
#pragma unroll
    for (int r = 0; r < 16; ++r) {
        const int row = (r & 3) + 8 * (r >> 2) + 4 * lh;
        const int co = 32 * og + row;
        const size_t o = (((size_t)n * C_ + co) << 12) + (y << 6);
        c2v[r] = acc[r] + bias[co] + res[o + 32 * ph + lm];
    }
    // pooled c2-half (channel-pair means)
#pragma unroll
    for (int q = 0; q < 4; ++q) {
        const int pc = 16 * og + 4 * q + 2 * lh;   // pooled channel (0..63)
        const size_t po = (((size_t)n * 64 + pc) << 12) + (y << 6);
        poolC2[po + 32 * ph + lm]        = 0.5f * (c2v[4 * q] + c2v[4 * q + 1]);
        poolC2[po + 4096 + 32 * ph + lm] = 0.5f * (c2v[4 * q + 2] + c2v[4 * q + 3]);
    }

    // fused sign: build S row [64 px][256 ch] bytes in LDS, then store
    __syncthreads();
#pragma unroll
    for (int q = 0; q < 4; ++q) {
        const int co0 = 32 * og + 8 * q + 4 * lh;
        const float b0 = b1v[n * 256 + 128 + co0];
        const float b1b = b1v[n * 256 + 128 + co0 + 1];
        const float b2b = b1v[n * 256 + 128 + co0 + 2];
        const float b3b = b1v[n * 256 + 128 + co0 + 3];
        union { int8_t b[4]; int u; } p0;
        p0.b[0] = sgn8(c2v[4 * q] + b0);
        p0.b[1] = sgn8(c2v[4 * q + 1] + b1b);
        p0.b[2] = sgn8(c2v[4 * q + 2] + b2b);
        p0.b[3] = sgn8(c2v[4 * q + 3] + b3b);
        *(int*)(lds + (32 * ph + lm) * COLB + 128 + co0) = p0.u;
    }
#pragma unroll
    for (int u = 0; u < 4; ++u) {
        int idx = u * 512 + tid;
        int ch = idx >> 4, seg = idx & 15;
        float4 v = *(const float4*)(xin + (((size_t)(n * C_ + ch)) << 12) + (y << 6) + 4 * seg);
        const float bv = b1v[n * 256 + ch];
        lds[(4 * seg) * COLB + ch]     = sgn8(v.x + bv);
        lds[(4 * seg + 1) * COLB + ch] = sgn8(v.y + bv);
        lds[(4 * seg + 2) * COLB + ch] = sgn8(v.z + bv);
        lds[(4 * seg + 3) * COLB + ch] = sgn8(v.w + bv);
    }
    __syncthreads();
    int8_t* Srow = S + ((size_t)(n * HW_) + (y << 6)) * C2_;
#pragma unroll
    for (int u = 0; u < 2; ++u) {
        int idx = u * 512 + tid;
        int px = idx >> 4, c16 = idx & 15;
        *(int4*)(Srow + (size_t)px * C2_ + 16 * c16) = *(const int4*)(lds + px * COLB + 16 * c16);
    }
}

// ---- binary conv: i8 K=32 MFMA + fused BN stats (512 thr) ----
__global__ __launch_bounds__(512, 4) void k_bconv(
    const int8_t* __restrict__ S,
    const int8_t* __restrict__ Wk,
    const float* __restrict__ alpha,
    const float* __restrict__ bias,
    float* __restrict__ out,
    float* __restrict__ bnS, float* __restrict__ bnQ) {
    __shared__ __align__(16) char lds[LDSZ];
    const int y = blockIdx.x;
    const int n = blockIdx.y;
    const int tid = threadIdx.x;
    const char* base = (const char*)(S + ((size_t)n * 64) * 64 * C2_);
    const char* r0 = (y > 0)  ? base + (size_t)(y - 1) * 16384 : nullptr;
    const char* r1 = base + (size_t)y * 16384;
    const char* r2 = (y < 63) ? base + (size_t)(y + 1) * 16384 : nullptr;
    if (tid < 96) {
        int r = tid / 32, q = tid & 31;
        int c = (q >> 4) ? 65 : 0, o = q & 15;
        *(float4*)(lds + (r * 66 + c) * COLB + o * 16) = make_float4(0.f, 0.f, 0.f, 0.f);
    }
    {
        const char* rs0 = r0; const char* rs1 = r1; const char* rs2 = r2;
#pragma unroll
        for (int it = 0; it < 2; ++it) {
            int idx = it * 512 + tid;   // 0..1023
            int x = idx >> 4, o = idx & 15;
            char* d0 = lds + (0 * 66 + x + 1) * COLB + o * 16;
            char* d1 = lds + (1 * 66 + x + 1) * COLB + o * 16;
            char* d2 = lds + (2 * 66 + x + 1) * COLB + o * 16;
            if (rs0) *(float4*)d0 = *(const float4*)(rs0 + x * 256 + o * 16);
            else     *(float4*)d0 = make_float4(0.f, 0.f, 0.f, 0.f);
            *(float4*)d1 = *(const float4*)(rs1 + x * 256 + o * 16);
            if (rs2) *(float4*)d2 = *(const float4*)(rs2 + x * 256 + o * 16);
            else     *(float4*)d2 = make_float4(0.f, 0.f, 0.f, 0.f);
        }
    }
    __syncthreads();

    const int w = tid >> 6;
    const int og = w >> 1;
    const int ph = w & 1;
    const int l = tid & 63;
    const int lm = l & 31;
    const int lh = l >> 5;

    v16i acc;
#pragma unroll
    for (int i = 0; i < 16; ++i) acc[i] = 0;

#pragma unroll
    for (int kk = 0; kk < 9; ++kk) {
        const int r = kk / 3, dx = kk % 3 - 1;
        const char* col = lds + (r * 66 + 32 * ph + lm + 1 + dx) * COLB + 16 * lh;
        const int8_t* wbase = Wk + (size_t)(kk * 16 + lh) * C_ * 16 + (32 * og + lm) * 16;
#pragma unroll
        for (int s = 0; s < 8; ++s) {
            v4i a = *(const v4i*)(wbase + (size_t)(2 * s) * C_ * 16);
            v4i b = *(const v4i*)(col + 32 * s);
            acc = __builtin_amdgcn_mfma_i32_32x32x32_i8(a, b, acc, 0, 0, 0);
        }
    }
    __syncthreads();   // staging consumed; reuse LDS for stats
    float* ldsS = (float*)lds;          // [2][128]
    float* ldsQ = (float*)lds + 256;    // [2][128]
#pragma unroll
    for (int r = 0; r < 16; ++r) {
        const int row = (r & 3) + 8 * (r >> 2) + 4 * lh;
        const int co = 32 * og + row;
        const float av = alpha[co], bv = bias[co];
        const size_t o = (((size_t)n * C_ + co) << 12) + (y << 6);
        float v = av * (float)acc[r] + bv;
        out[o + 32 * ph + lm] = v;
        float p = v, q = v * v;
#pragma unroll
        for (int m = 16; m > 0; m >>= 1) {
            p += __shfl_xor(p, m, 64);
            q += __shfl_xor(q, m, 64);
        }
        if (lm == 0) { ldsS[ph * 128 + co] = p; ldsQ[ph * 128 + co] = q; }
    }
    __syncthreads();
    if (tid < 128) {
        atomicAdd(&bnS[tid], ldsS[tid] + ldsS[128 + tid]);
        atomicAdd(&bnQ[tid], ldsQ[tid] + ldsQ[128 + tid]);
    }
}

// ---- final epilogue, float4 ----
__global__ __launch_bounds__(256) void k_final(const float* __restrict__ y3,
                                               const float* __restrict__ x,
                                               const float* __restrict__ poolC2,
                                               const float* __restrict__ bnS,
                                               const float* __restrict__ bnQ,
                                               const float* __restrict__ bng,
                                               const float* __restrict__ bnb,
                                               const float* __restrict__ b2v,
                                               const float* __restrict__ pa,
                                               const float* __restrict__ b3v,
                                               float* __restrict__ out) {
    const int idx4 = blockIdx.x * 256 + threadIdx.x;   // < 1,048,576
    const int hw = (idx4 & 1023) * 4;
    const int cb = idx4 >> 10;
    const int co = cb & 127;
    const int n = cb >> 7;
    const float mu = bnS[co] * (1.f / 32768.f);
    const float var = bnQ[co] * (1.f / 32768.f) - mu * mu;
    const float rstd = rsqrtf(var + EPS_);
    const float gm = rstd * bng[co];
    const float bt = bnb[co] - mu * gm;
    const size_t obase = (((size_t)(n * C_ + co)) << 12) + hw;
    float4 v = *(const float4*)(y3 + obase);
    v.x = v.x * gm + bt; v.y = v.y * gm + bt; v.z = v.z * gm + bt; v.w = v.w * gm + bt;

    float4 pv;
    if (co < 64) {
        const int ch0 = 2 * co;
        float4 pA = *(const float4*)(x + (((size_t)(n * C_ + ch0)) << 12) + hw);
        float4 pB = *(const float4*)(x + (((size_t)(n * C_ + ch0 + 1)) << 12) + hw);
        pv.x = 0.5f * (pA.x + pB.x); pv.y = 0.5f * (pA.y + pB.y);
        pv.z = 0.5f * (pA.z + pB.z); pv.w = 0.5f * (pA.w + pB.w);
    } else {
        pv = *(const float4*)(poolC2 + (((size_t)(n * 64 + co - 64)) << 12) + hw);
    }
    const float bias2 = b2v[n * 128 + co];
    const float aP = pa[co];
    const float bias3 = b3v[n * 128 + co];
    float4 r;
    float t;
    t = v.x + pv.x + bias2; t = (t >= 0.f) ? t : aP * t; r.x = t + bias3;
    t = v.y + pv.y + bias2; t = (t >= 0.f) ? t : aP * t; r.y = t + bias3;
    t = v.z + pv.z + bias2; t = (t >= 0.f) ? t : aP * t; r.z = t + bias3;
    t = v.w + pv.w + bias2; t = (t >= 0.f) ? t : aP * t; r.w = t + bias3;
    *(float4*)(out + obase) = r;
}

// ---------------- launch ----------------
extern "C" void kernel_launch(void* const* d_in, const int* in_sizes, int n_in,
                              void* d_out, int out_size, void* d_ws, size_t ws_size,
                              hipStream_t stream) {
    const float* c       = (const float*)d_in[0];
    const float* x       = (const float*)d_in[1];
    const float* emb     = (const float*)d_in[2];
    const float* gn1_g   = (const float*)d_in[3];
    const float* gn1_b   = (const float*)d_in[4];
    const float* conv1_w = (const float*)d_in[5];
    const float* conv1_b = (const float*)d_in[6];
    const float* emb_w   = (const float*)d_in[7];
    const float* emb_b   = (const float*)d_in[8];
    const float* gn2_g   = (const float*)d_in[9];
    const float* gn2_b   = (const float*)d_in[10];
    const float* conv2_w = (const float*)d_in[11];
    const float* conv2_b = (const float*)d_in[12];
    const float* m1_w    = (const float*)d_in[13];
    const float* m1_b    = (const float*)d_in[14];
    const float* bconv_w = (const float*)d_in[15];
    const float* bconv_b = (const float*)d_in[16];
    const float* bn_g    = (const float*)d_in[17];
    const float* bn_b    = (const float*)d_in[18];
    const float* m2_w    = (const float*)d_in[19];
    const float* m2_b    = (const float*)d_in[20];
    const float* prelu_a = (const float*)d_in[21];
    const float* m3_w    = (const float*)d_in[22];
    const float* m3_b    = (const float*)d_in[23];
    float* out = (float*)d_out;

    float* ws = (float*)d_ws;
    const size_t NCHW = (size_t)B_ * C_ * HW_;       // 4,194,304
    float*  poolC2 = ws;
    float*  y_buf = ws + NCHW;          // conv1 NHWC fp32, later bconv NCHW out
    int8_t* S     = (int8_t*)(ws + 2 * NCHW);                  // 8 MB
    int8_t* sgn   = (int8_t*)(ws + 2 * NCHW + NCHW / 2);
    unsigned short* Wc1 = (unsigned short*)(ws + 2 * NCHW + NCHW / 2 + 73728);
    unsigned short* Wc2 = Wc1 + C_ * C_ * 9;
    float*  alpha = ws + 2 * NCHW + NCHW / 2 + 73728 + 2 * 73728;
    float*  eo    = alpha + 128;
    float*  b1v   = eo + B_ * 256;
    float*  b2v   = b1v + B_ * 256;
    float*  b3v   = b2v + B_ * 128;
    float*  bnS   = b3v + B_ * 128;
    float*  bnQ   = bnS + 128;
    float*  gnS   = bnQ + 128;   // 256
    float*  gnQ   = gnS + 256;   // 256
    float*  g1S   = gnQ + 256;   // 256
    float*  g1Q   = g1S + 256;   // 256

    k_prep<<<1152, 256, 0, stream>>>(bconv_w, sgn, alpha, bnS, bnQ, gnS, gnQ,
                                     conv1_w, conv2_w, Wc1, Wc2,
                                     emb, emb_w, emb_b, m1_w, m1_b, m2_w, m2_b,
                                     m3_w, m3_b, eo, b1v, b2v, b3v,
                                     c, g1S, g1Q);
    k_conv1<<<dim3(64, B_), 512, 0, stream>>>(c, Wc1, conv1_b, gn1_g, gn1_b,
                                              g1S, g1Q, y_buf, gnS, gnQ);
    k_conv2<<<dim3(64, B_), 512, 0, stream>>>(y_buf, Wc2, conv2_b, c, x, b1v, eo,
                                              gn2_g, gn2_b, gnS, gnQ, poolC2, S);
    k_bconv<<<dim3(64, B_), 512, 0, stream>>>(S, sgn, alpha, bconv_b, y_buf, bnS, bnQ);
    k_final<<<NCHW / 1024, 256, 0, stream>>>(y_buf, x, poolC2, bnS, bnQ, bn_g, bn_b,
                                             b2v, prelu_a, b3v, out);
}

// Round 6
// 216.334 us; speedup vs baseline: 2.1746x; 1.0137x over previous
//
#include <hip/hip_runtime.h>
#include <stdint.h>

// ConcatLayer_55654186221983 on MI355X (gfx950). All fp32 I/O.
// B=8, C=128, C2=256, H=W=64, EMB=512, GROUPS=32, EPS=1e-5.
// R15 (on R14's 219us): (a) S stored in padded LDS-image layout (66x272B
//      cols) with zeroed guard rows -> bconv staging = contiguous async
//      global_load_lds DMA, no VALU/branches; (b) conv1 staging float4
//      loads + paired-u32 LDS writes (1/4 load insts, 1/2 write insts);
//      (c) GN1 stats split into hw-halves (512 blocks, conv1 sums parts).

#define B_   8
#define C_   128
#define C2_  256
#define HW_  4096
#define EMB_ 512
#define EPS_ 1e-5f

typedef int   v16i __attribute__((ext_vector_type(16)));
typedef float v16f __attribute__((ext_vector_type(16)));
typedef short v8s  __attribute__((ext_vector_type(8)));
typedef int   v4i  __attribute__((ext_vector_type(4)));

// LDS tile: 3 rows x 66 cols x (256 data + 16 pad) bytes
#define COLB 272
#define ROWB (66 * COLB)          // 17952 B per padded row
#define LDSZ 55296                // >= 53*1024 gload_lds dest span
#define TSTRIDE 132

__device__ __forceinline__ float silu(float v) {
    return v * __builtin_amdgcn_rcpf(1.f + __expf(-v));
}
__device__ __forceinline__ unsigned short f2bf(float f) {
    unsigned int x = __float_as_uint(f);
    return (unsigned short)((x + 0x7FFFu + ((x >> 16) & 1u)) >> 16);  // RNE
}
__device__ __forceinline__ int8_t sgn8(float v) {
    return (v > 0.f) ? (int8_t)1 : ((v < 0.f) ? (int8_t)(-1) : (int8_t)0);
}
__device__ __forceinline__ void gld16(char* ldst, const char* gsrc) {
    // async global->LDS: dest = wave-uniform base + lane*16 (HW-applied)
    __builtin_amdgcn_global_load_lds((const unsigned int*)gsrc,
                                     (unsigned int*)ldst, 16, 0, 0);
}

// ---- merged prep + embedding + GN1-stats-halves + S-guard-zero ----
__global__ __launch_bounds__(256) void k_prep(
    const float* __restrict__ w, int8_t* __restrict__ sgn,
    float* __restrict__ alpha, float* __restrict__ bnS, float* __restrict__ bnQ,
    float* __restrict__ gnS, float* __restrict__ gnQ,
    const float* __restrict__ w1, const float* __restrict__ w2,
    unsigned short* __restrict__ Wc1, unsigned short* __restrict__ Wc2,
    const float* __restrict__ emb,
    const float* __restrict__ ew, const float* __restrict__ ebb,
    const float* __restrict__ m1w, const float* __restrict__ m1b,
    const float* __restrict__ m2w, const float* __restrict__ m2b,
    const float* __restrict__ m3w, const float* __restrict__ m3b,
    float* __restrict__ eo, float* __restrict__ b1,
    float* __restrict__ b2, float* __restrict__ b3,
    const float* __restrict__ gin,
    float* __restrict__ g1S, float* __restrict__ g1Q,
    int8_t* __restrict__ S) {
    __shared__ float red[256];
    const int blk = blockIdx.x, tid = threadIdx.x;
    if (blk < 128) {
        const int o = blk;
        if (o == 0 && tid < 128) { bnS[tid] = 0.f; bnQ[tid] = 0.f; }
        if (o == 1) { gnS[tid] = 0.f; }
        if (o == 2) { gnQ[tid] = 0.f; }
        const float* wr = w + (size_t)o * (C2_ * 9);
        float s = 0.f;
        for (int i = tid; i < C2_ * 9; i += 256) s += fabsf(wr[i]);
        red[tid] = s;
        __syncthreads();
        for (int st = 128; st > 0; st >>= 1) {
            if (tid < st) red[tid] += red[tid + st];
            __syncthreads();
        }
        if (tid == 0) alpha[o] = red[0] / (float)(C2_ * 9);
        for (int kk = 0; kk < 9; ++kk) {
            float v = wr[tid * 9 + kk];   // tid == ci
            sgn[((size_t)(kk * 16 + (tid >> 4)) * C_ + o) * 16 + (tid & 15)] = sgn8(v);
        }
    } else if (blk < 704) {
        int i = (blk - 128) * 256 + tid;
        int co = i / (C_ * 9);
        int rem = i - co * (C_ * 9);
        int ci = rem / 9, kk = rem - ci * 9;
        size_t d = ((size_t)(kk * 16 + (ci >> 3)) * C_ + co) * 8 + (ci & 7);
        Wc1[d] = f2bf(w1[i]);
        Wc2[d] = f2bf(w2[i]);
    } else if (blk < 896) {
        const int o = (blk - 704) * 4 + (tid >> 6);   // 0..767
        const int l = tid & 63;
        const float* wv;
        float bias;
        float* dst;
        int dstride;
        if (o < 256)      { wv = ew  + (size_t)o * EMB_;              bias = ebb[o];    dst = eo + o;  dstride = 256; }
        else if (o < 512) { int r = o - 256; wv = m1w + (size_t)r * EMB_; bias = m1b[r]; dst = b1 + r; dstride = 256; }
        else if (o < 640) { int r = o - 512; wv = m2w + (size_t)r * EMB_; bias = m2b[r]; dst = b2 + r; dstride = 128; }
        else              { int r = o - 640; wv = m3w + (size_t)r * EMB_; bias = m3b[r]; dst = b3 + r; dstride = 128; }
        const float4 wa = *(const float4*)(wv + 8 * l);
        const float4 wb = *(const float4*)(wv + 8 * l + 4);
#pragma unroll
        for (int b = 0; b < B_; ++b) {
            const float* s = emb + b * EMB_ + 8 * l;
            float4 sa = *(const float4*)(s);
            float4 sb = *(const float4*)(s + 4);
            float p = wa.x * silu(sa.x) + wa.y * silu(sa.y) + wa.z * silu(sa.z) + wa.w * silu(sa.w) +
                      wb.x * silu(sb.x) + wb.y * silu(sb.y) + wb.z * silu(sb.z) + wb.w * silu(sb.w);
#pragma unroll
            for (int off = 32; off > 0; off >>= 1) p += __shfl_down(p, off, 64);
            if (l == 0) dst[b * dstride] = bias + p;
        }
    } else if (blk < 1408) {
        // GN1 stats, hw-halves: block = (n, grp, h); conv1 sums both parts
        const int idx = blk - 896;
        const int n = idx >> 6, rest = idx & 63, grp = rest >> 1, h = rest & 1;
        const size_t base = ((size_t)(n * C_ + grp * 4)) << 12;
        float sum = 0.f, sq = 0.f;
        const float4* in4 = (const float4*)(gin + base);
        for (int i = tid + h * 2048; i < (h + 1) * 2048; i += 256) {
            float4 v = in4[i];
            sum += v.x + v.y + v.z + v.w;
            sq += v.x * v.x + v.y * v.y + v.z * v.z + v.w * v.w;
        }
#pragma unroll
        for (int off = 32; off > 0; off >>= 1) {
            sum += __shfl_xor(sum, off, 64);
            sq  += __shfl_xor(sq, off, 64);
        }
        if ((tid & 63) == 0) { red[tid >> 6] = sum; red[8 + (tid >> 6)] = sq; }
        __syncthreads();
        if (tid == 0) {
            g1S[h * 256 + n * 32 + grp] = red[0] + red[1] + red[2] + red[3];
            g1Q[h * 256 + n * 32 + grp] = red[8] + red[9] + red[10] + red[11];
        }
    } else {
        // zero S guard rows (row 0 and row 65 per n)
        const int u = blk - 1408;       // 0..15
        const int n = u >> 1;
        const int row = (u & 1) * 65;
        int4* base = (int4*)(S + (size_t)n * 66 * ROWB + (size_t)row * ROWB);
        const int4 z = make_int4(0, 0, 0, 0);
        for (int i = tid; i < ROWB / 16; i += 256) base[i] = z;
    }
}

// ---- conv1: stages GN1+SiLU+bf16 from NCHW c (float4 loads, u32-pair
//      writes); bf16 MFMA; GN2 stats; writes y NHWC fp32. ----
__global__ __launch_bounds__(512, 4) void k_conv1(
    const float* __restrict__ cin,
    const unsigned short* __restrict__ Wc,
    const float* __restrict__ bias,
    const float* __restrict__ g1w, const float* __restrict__ g1b,
    const float* __restrict__ g1S, const float* __restrict__ g1Q,
    float* __restrict__ outN,
    float* __restrict__ gnS, float* __restrict__ gnQ) {
    __shared__ __align__(16) char lds[LDSZ];
    __shared__ float chA[128], chB[128];
    const int y = blockIdx.x;
    const int n = blockIdx.y;
    const int tid = threadIdx.x;

    if (tid < 128) {   // GN1 per-channel affine: act = silu(v*A + B)
        const int ch = tid, grp = tid >> 2;
        const float s1 = g1S[n * 32 + grp] + g1S[256 + n * 32 + grp];
        const float q1 = g1Q[n * 32 + grp] + g1Q[256 + n * 32 + grp];
        const float mu = s1 * (1.f / 16384.f);
        const float var = q1 * (1.f / 16384.f) - mu * mu;
        const float rstd = rsqrtf(var + EPS_);
        const float A = g1w[ch] * rstd;
        chA[ch] = A;
        chB[ch] = g1b[ch] - mu * A;
    }
    if (tid < 96) {   // zero pad columns 0 and 65
        int r = tid / 32, q = tid & 31;
        int c = (q >> 4) ? 65 : 0, o = q & 15;
        *(float4*)(lds + (r * 66 + c) * COLB + o * 16) = make_float4(0.f, 0.f, 0.f, 0.f);
    }
    __syncthreads();

    // staging: unit = (row r, ch-pair cp, px-quad s4); float4 loads from 2
    // planes, 4 packed u32 LDS writes (lo=ch0, hi=ch0+1)
    union F4 { float4 v; float f[4]; };
#pragma unroll
    for (int u = 0; u < 6; ++u) {
        int unit = u * 512 + tid;        // 0..3071 = 3 x 64cp x 16s4
        int r = unit >> 10, rem = unit & 1023;
        int cp = rem >> 4, s4 = rem & 15;
        int ch0 = 2 * cp;
        int yy = y - 1 + r;
        char* dst0 = lds + (r * 66 + 4 * s4 + 1) * COLB + 4 * cp;
        if (yy >= 0 && yy < 64) {
            const float* src = cin + (((size_t)(n * C_ + ch0)) << 12) + yy * 64 + 4 * s4;
            F4 fa, fb;
            fa.v = *(const float4*)src;
            fb.v = *(const float4*)(src + HW_);
            const float A0 = chA[ch0], B0 = chB[ch0];
            const float A1 = chA[ch0 + 1], B1 = chB[ch0 + 1];
#pragma unroll
            for (int e = 0; e < 4; ++e) {
                unsigned int lo = f2bf(silu(fa.f[e] * A0 + B0));
                unsigned int hi = f2bf(silu(fb.f[e] * A1 + B1));
                *(unsigned int*)(dst0 + e * COLB) = lo | (hi << 16);
            }
        } else {
#pragma unroll
            for (int e = 0; e < 4; ++e)
                *(unsigned int*)(dst0 + e * COLB) = 0u;
        }
    }
    __syncthreads();

    const int w = tid >> 6;
    const int og = w >> 1;     // och group (32 ch)
    const int ph = w & 1;      // px half (32 px)
    const int l = tid & 63;
    const int lm = l & 31;
    const int lh = l >> 5;

    v16f acc;
#pragma unroll
    for (int i = 0; i < 16; ++i) acc[i] = 0.f;

#pragma unroll
    for (int kk = 0; kk < 9; ++kk) {
        const int r = kk / 3, dx = kk % 3 - 1;
        const char* col = lds + (r * 66 + 32 * ph + lm + 1 + dx) * COLB + 16 * lh;
        const unsigned short* wbase = Wc + (size_t)(kk * 16 + lh) * C_ * 8 + (32 * og + lm) * 8;
#pragma unroll
        for (int cb = 0; cb < 8; ++cb) {
            v8s a = *(const v8s*)(wbase + (size_t)(2 * cb) * C_ * 8);
            v8s b = *(const v8s*)(col + 32 * cb);
            acc = __builtin_amdgcn_mfma_f32_32x32x16_bf16(a, b, acc, 0, 0, 0);
        }
    }
    __syncthreads();   // staging LDS fully consumed; reuse for transpose+stats
    float* ldsT = (float*)lds;                        // [64][TSTRIDE]
    float* ldsS = (float*)(lds + 64 * TSTRIDE * 4);   // [2][128]
    float* ldsQ = ldsS + 256;                         // [2][128]
#pragma unroll
    for (int r = 0; r < 16; ++r) {
        const int row = (r & 3) + 8 * (r >> 2) + 4 * lh;
        const int co = 32 * og + row;
        float v = acc[r] + bias[co];
        ldsT[(32 * ph + lm) * TSTRIDE + co] = v;
        float p = v, q = v * v;
#pragma unroll
        for (int m = 16; m > 0; m >>= 1) {
            p += __shfl_xor(p, m, 64);
            q += __shfl_xor(q, m, 64);
        }
        if (lm == 0) { ldsS[ph * 128 + co] = p; ldsQ[ph * 128 + co] = q; }
    }
    __syncthreads();
    if (tid < 32) {
        const int g = tid;
        float p = 0.f, q = 0.f;
#pragma unroll
        for (int j = 0; j < 4; ++j) {
            p += ldsS[4 * g + j] + ldsS[128 + 4 * g + j];
            q += ldsQ[4 * g + j] + ldsQ[128 + 4 * g + j];
        }
        atomicAdd(&gnS[n * 32 + g], p);
        atomicAdd(&gnQ[n * 32 + g], q);
    }
    // coalesced NHWC store
    const int q4 = tid & 31;
    float* orow = outN + (((size_t)(n * HW_) + (y << 6)) << 7);
#pragma unroll
    for (int it = 0; it < 4; ++it) {
        const int px = it * 16 + (tid >> 5);
        *(float4*)(orow + ((size_t)px << 7) + 4 * q4) =
            *(const float4*)(ldsT + px * TSTRIDE + 4 * q4);
    }
}

// ---- conv2: stages GN2+FiLM+SiLU from NHWC fp32 y; MFMA; sign+pool;
//      writes S in padded LDS-image layout (guard-row indexed) ----
__global__ __launch_bounds__(512, 4) void k_conv2(
    const float* __restrict__ yin,  // NHWC
    const unsigned short* __restrict__ Wc,
    const float* __restrict__ bias,
    const float* __restrict__ res,
    const float* __restrict__ xin,
    const float* __restrict__ b1v,
    const float* __restrict__ eo,
    const float* __restrict__ g2,
    const float* __restrict__ bt2,
    const float* __restrict__ gnS,
    const float* __restrict__ gnQ,
    float* __restrict__ poolC2,
    int8_t* __restrict__ S) {
    __shared__ __align__(16) char lds[LDSZ];
    __shared__ float ldsA[128], ldsB[128];
    const int y = blockIdx.x;
    const int n = blockIdx.y;
    const int tid = threadIdx.x;

    if (tid < 128) {
        const int ch = tid, grp = tid >> 2;
        const float mu = gnS[n * 32 + grp] * (1.f / 16384.f);
        const float var = gnQ[n * 32 + grp] * (1.f / 16384.f) - mu * mu;
        const float rstd = rsqrtf(var + EPS_);
        const float gg = g2[ch] * rstd;
        const float sc = 1.f + eo[n * 256 + ch];
        ldsA[ch] = gg * sc;
        ldsB[ch] = (bt2[ch] - mu * gg) * sc + eo[n * 256 + 128 + ch];
    }
    if (tid < 96) {
        int r = tid / 32, q = tid & 31;
        int cpad = (q >> 4) ? 65 : 0, o = q & 15;
        *(float4*)(lds + (r * 66 + cpad) * COLB + o * 16) = make_float4(0.f, 0.f, 0.f, 0.f);
    }
    __syncthreads();

    // staging from NHWC: thread owns channel-quad qc; affine coeffs hoisted
    const int qc = tid & 31;
    const float A0 = ldsA[4 * qc], A1 = ldsA[4 * qc + 1], A2 = ldsA[4 * qc + 2], A3 = ldsA[4 * qc + 3];
    const float B0 = ldsB[4 * qc], B1 = ldsB[4 * qc + 1], B2 = ldsB[4 * qc + 2], B3 = ldsB[4 * qc + 3];
#pragma unroll
    for (int r = 0; r < 3; ++r) {
        const int yy = y - 1 + r;
        const float* ysrc = yin + (((size_t)(n * HW_) + yy * 64) << 7);
        const bool ok = (yy >= 0 && yy < 64);
#pragma unroll
        for (int it = 0; it < 4; ++it) {
            const int px = it * 16 + (tid >> 5);
            char* dst = lds + (r * 66 + px + 1) * COLB + qc * 8;
            if (ok) {
                float4 v = *(const float4*)(ysrc + ((size_t)px << 7) + 4 * qc);
                union { unsigned short u[4]; uint2 q; } pk;
                pk.u[0] = f2bf(silu(v.x * A0 + B0));
                pk.u[1] = f2bf(silu(v.y * A1 + B1));
                pk.u[2] = f2bf(silu(v.z * A2 + B2));
                pk.u[3] = f2bf(silu(v.w * A3 + B3));
                *(uint2*)dst = pk.q;
            } else {
                *(uint2*)dst = make_uint2(0u, 0u);
            }
        }
    }
    __syncthreads();

    const int w = tid >> 6;
    const int og = w >> 1;
    const int ph = w & 1;
    const int l = tid & 63;
    const int lm = l & 31;
    const int lh = l >> 5;

    v16f acc;
#pragma unroll
    for (int i = 0; i < 16; ++i) acc[i] = 0.f;

#pragma unroll
    for (int kk = 0; kk < 9; ++kk) {
        const int r = kk / 3, dx = kk % 3 - 1;
        const char* col = lds + (r * 66 + 32 * ph + lm + 1 + dx) * COLB + 16 * lh;
        const unsigned short* wbase = Wc + (size_t)(kk * 16 + lh) * C_ * 8 + (32 * og + lm) * 8;
#pragma unroll
        for (int cb = 0; cb < 8; ++cb) {
            v8s a = *(const v8s*)(wbase + (size_t)(2 * cb) * C_ * 8);
            v8s b = *(const v8s*)(col + 32 * cb);
            acc = __builtin_amdgcn_mfma_f32_32x32x16_bf16(a, b, acc, 0, 0, 0);
        }
    }
    float c2v[16];
#pragma unroll
    for (int r = 0; r < 16; ++r) {
        const int row = (r & 3) + 8 * (r >> 2) + 4 * lh;
        const int co = 32 * og + row;
        const size_t o = (((size_t)n * C_ + co) << 12) + (y << 6);
        c2v[r] = acc[r] + bias[co] + res[o + 32 * ph + lm];
    }
    // pooled c2-half (channel-pair means)
#pragma unroll
    for (int q = 0; q < 4; ++q) {
        const int pc = 16 * og + 4 * q + 2 * lh;   // pooled channel (0..63)
        const size_t po = (((size_t)n * 64 + pc) << 12) + (y << 6);
        poolC2[po + 32 * ph + lm]        = 0.5f * (c2v[4 * q] + c2v[4 * q + 1]);
        poolC2[po + 4096 + 32 * ph + lm] = 0.5f * (c2v[4 * q + 2] + c2v[4 * q + 3]);
    }

    // fused sign: build padded S row image in LDS (cols 1..64 data,
    // cols 0/65 zero), then linear copy out
    __syncthreads();
#pragma unroll
    for (int q = 0; q < 4; ++q) {
        const int co0 = 32 * og + 8 * q + 4 * lh;
        const float b0 = b1v[n * 256 + 128 + co0];
        const float b1b = b1v[n * 256 + 128 + co0 + 1];
        const float b2b = b1v[n * 256 + 128 + co0 + 2];
        const float b3b = b1v[n * 256 + 128 + co0 + 3];
        union { int8_t b[4]; int u; } p0;
        p0.b[0] = sgn8(c2v[4 * q] + b0);
        p0.b[1] = sgn8(c2v[4 * q + 1] + b1b);
        p0.b[2] = sgn8(c2v[4 * q + 2] + b2b);
        p0.b[3] = sgn8(c2v[4 * q + 3] + b3b);
        *(int*)(lds + (32 * ph + lm + 1) * COLB + 128 + co0) = p0.u;
    }
#pragma unroll
    for (int u = 0; u < 4; ++u) {
        int idx = u * 512 + tid;
        int ch = idx >> 4, seg = idx & 15;
        float4 v = *(const float4*)(xin + (((size_t)(n * C_ + ch)) << 12) + (y << 6) + 4 * seg);
        const float bv = b1v[n * 256 + ch];
        lds[(4 * seg + 1) * COLB + ch]     = sgn8(v.x + bv);
        lds[(4 * seg + 2) * COLB + ch] = sgn8(v.y + bv);
        lds[(4 * seg + 3) * COLB + ch] = sgn8(v.z + bv);
        lds[(4 * seg + 4) * COLB + ch] = sgn8(v.w + bv);
    }
    if (tid < 34) {   // zero columns 0 and 65 (17 x 16B each)
        int c = tid / 17, o = tid - c * 17;
        *(float4*)(lds + (c ? 65 : 0) * COLB + o * 16) = make_float4(0.f, 0.f, 0.f, 0.f);
    }
    __syncthreads();
    int4* Srow = (int4*)(S + (size_t)n * 66 * ROWB + (size_t)(y + 1) * ROWB);
    const int4* lsrc = (const int4*)lds;
    for (int i = tid; i < ROWB / 16; i += 512) Srow[i] = lsrc[i];
}

// ---- binary conv: async gload_lds staging + i8 MFMA + fused BN stats ----
__global__ __launch_bounds__(512, 4) void k_bconv(
    const int8_t* __restrict__ S,
    const int8_t* __restrict__ Wk,
    const float* __restrict__ alpha,
    const float* __restrict__ bias,
    float* __restrict__ out,
    float* __restrict__ bnS, float* __restrict__ bnQ) {
    __shared__ __align__(16) char lds[LDSZ];
    const int y = blockIdx.x;
    const int n = blockIdx.y;
    const int tid = threadIdx.x;
    // rows y-1..y+1 in guard space = contiguous 3*ROWB at row index y
    const char* src3 = (const char*)S + (size_t)n * 66 * ROWB + (size_t)y * ROWB;
    const int wave = tid >> 6, lane = tid & 63;
    for (int u = wave; u < 53; u += 8)      // 53*1024 >= 3*ROWB
        gld16(lds + u * 1024, src3 + u * 1024 + lane * 16);
    __syncthreads();

    const int w = tid >> 6;
    const int og = w >> 1;
    const int ph = w & 1;
    const int l = tid & 63;
    const int lm = l & 31;
    const int lh = l >> 5;

    v16i acc;
#pragma unroll
    for (int i = 0; i < 16; ++i) acc[i] = 0;

#pragma unroll
    for (int kk = 0; kk < 9; ++kk) {
        const int r = kk / 3, dx = kk % 3 - 1;
        const char* col = lds + (r * 66 + 32 * ph + lm + 1 + dx) * COLB + 16 * lh;
        const int8_t* wbase = Wk + (size_t)(kk * 16 + lh) * C_ * 16 + (32 * og + lm) * 16;
#pragma unroll
        for (int s = 0; s < 8; ++s) {
            v4i a = *(const v4i*)(wbase + (size_t)(2 * s) * C_ * 16);
            v4i b = *(const v4i*)(col + 32 * s);
            acc = __builtin_amdgcn_mfma_i32_32x32x32_i8(a, b, acc, 0, 0, 0);
        }
    }
    __syncthreads();   // staging consumed; reuse LDS for stats
    float* ldsS = (float*)lds;          // [2][128]
    float* ldsQ = (float*)lds + 256;    // [2][128]
#pragma unroll
    for (int r = 0; r < 16; ++r) {
        const int row = (r & 3) + 8 * (r >> 2) + 4 * lh;
        const int co = 32 * og + row;
        const float av = alpha[co], bv = bias[co];
        const size_t o = (((size_t)n * C_ + co) << 12) + (y << 6);
        float v = av * (float)acc[r] + bv;
        out[o + 32 * ph + lm] = v;
        float p = v, q = v * v;
#pragma unroll
        for (int m = 16; m > 0; m >>= 1) {
            p += __shfl_xor(p, m, 64);
            q += __shfl_xor(q, m, 64);
        }
        if (lm == 0) { ldsS[ph * 128 + co] = p; ldsQ[ph * 128 + co] = q; }
    }
    __syncthreads();
    if (tid < 128) {
        atomicAdd(&bnS[tid], ldsS[tid] + ldsS[128 + tid]);
        atomicAdd(&bnQ[tid], ldsQ[tid] + ldsQ[128 + tid]);
    }
}

// ---- final epilogue, float4 ----
__global__ __launch_bounds__(256) void k_final(const float* __restrict__ y3,
                                               const float* __restrict__ x,
                                               const float* __restrict__ poolC2,
                                               const float* __restrict__ bnS,
                                               const float* __restrict__ bnQ,
                                               const float* __restrict__ bng,
                                               const float* __restrict__ bnb,
                                               const float* __restrict__ b2v,
                                               const float* __restrict__ pa,
                                               const float* __restrict__ b3v,
                                               float* __restrict__ out) {
    const int idx4 = blockIdx.x * 256 + threadIdx.x;   // < 1,048,576
    const int hw = (idx4 & 1023) * 4;
    const int cb = idx4 >> 10;
    const int co = cb & 127;
    const int n = cb >> 7;
    const float mu = bnS[co] * (1.f / 32768.f);
    const float var = bnQ[co] * (1.f / 32768.f) - mu * mu;
    const float rstd = rsqrtf(var + EPS_);
    const float gm = rstd * bng[co];
    const float bt = bnb[co] - mu * gm;
    const size_t obase = (((size_t)(n * C_ + co)) << 12) + hw;
    float4 v = *(const float4*)(y3 + obase);
    v.x = v.x * gm + bt; v.y = v.y * gm + bt; v.z = v.z * gm + bt; v.w = v.w * gm + bt;

    float4 pv;
    if (co < 64) {
        const int ch0 = 2 * co;
        float4 pA = *(const float4*)(x + (((size_t)(n * C_ + ch0)) << 12) + hw);
        float4 pB = *(const float4*)(x + (((size_t)(n * C_ + ch0 + 1)) << 12) + hw);
        pv.x = 0.5f * (pA.x + pB.x); pv.y = 0.5f * (pA.y + pB.y);
        pv.z = 0.5f * (pA.z + pB.z); pv.w = 0.5f * (pA.w + pB.w);
    } else {
        pv = *(const float4*)(poolC2 + (((size_t)(n * 64 + co - 64)) << 12) + hw);
    }
    const float bias2 = b2v[n * 128 + co];
    const float aP = pa[co];
    const float bias3 = b3v[n * 128 + co];
    float4 r;
    float t;
    t = v.x + pv.x + bias2; t = (t >= 0.f) ? t : aP * t; r.x = t + bias3;
    t = v.y + pv.y + bias2; t = (t >= 0.f) ? t : aP * t; r.y = t + bias3;
    t = v.z + pv.z + bias2; t = (t >= 0.f) ? t : aP * t; r.z = t + bias3;
    t = v.w + pv.w + bias2; t = (t >= 0.f) ? t : aP * t; r.w = t + bias3;
    *(float4*)(out + obase) = r;
}

// ---------------- launch ----------------
extern "C" void kernel_launch(void* const* d_in, const int* in_sizes, int n_in,
                              void* d_out, int out_size, void* d_ws, size_t ws_size,
                              hipStream_t stream) {
    const float* c       = (const float*)d_in[0];
    const float* x       = (const float*)d_in[1];
    const float* emb     = (const float*)d_in[2];
    const float* gn1_g   = (const float*)d_in[3];
    const float* gn1_b   = (const float*)d_in[4];
    const float* conv1_w = (const float*)d_in[5];
    const float* conv1_b = (const float*)d_in[6];
    const float* emb_w   = (const float*)d_in[7];
    const float* emb_b   = (const float*)d_in[8];
    const float* gn2_g   = (const float*)d_in[9];
    const float* gn2_b   = (const float*)d_in[10];
    const float* conv2_w = (const float*)d_in[11];
    const float* conv2_b = (const float*)d_in[12];
    const float* m1_w    = (const float*)d_in[13];
    const float* m1_b    = (const float*)d_in[14];
    const float* bconv_w = (const float*)d_in[15];
    const float* bconv_b = (const float*)d_in[16];
    const float* bn_g    = (const float*)d_in[17];
    const float* bn_b    = (const float*)d_in[18];
    const float* m2_w    = (const float*)d_in[19];
    const float* m2_b    = (const float*)d_in[20];
    const float* prelu_a = (const float*)d_in[21];
    const float* m3_w    = (const float*)d_in[22];
    const float* m3_b    = (const float*)d_in[23];
    float* out = (float*)d_out;

    float* ws = (float*)d_ws;
    const size_t NCHW = (size_t)B_ * C_ * HW_;       // 4,194,304
    float*  poolC2 = ws;
    float*  y_buf = ws + NCHW;          // conv1 NHWC fp32, later bconv NCHW out
    int8_t* S     = (int8_t*)(ws + 2 * NCHW);   // padded: 8 x 66 x ROWB = 9.04MB
    const size_t S_f = (8 * 66 * (size_t)ROWB) / 4 + 256;   // +1KB slack (OOB reads)
    int8_t* sgn   = (int8_t*)(ws + 2 * NCHW + S_f);
    unsigned short* Wc1 = (unsigned short*)(ws + 2 * NCHW + S_f + 73728);
    unsigned short* Wc2 = Wc1 + C_ * C_ * 9;
    float*  alpha = ws + 2 * NCHW + S_f + 73728 + 2 * 73728;
    float*  eo    = alpha + 128;
    float*  b1v   = eo + B_ * 256;
    float*  b2v   = b1v + B_ * 256;
    float*  b3v   = b2v + B_ * 128;
    float*  bnS   = b3v + B_ * 128;
    float*  bnQ   = bnS + 128;
    float*  gnS   = bnQ + 128;   // 256
    float*  gnQ   = gnS + 256;   // 256
    float*  g1S   = gnQ + 256;   // 512 (two halves)
    float*  g1Q   = g1S + 512;   // 512

    k_prep<<<1424, 256, 0, stream>>>(bconv_w, sgn, alpha, bnS, bnQ, gnS, gnQ,
                                     conv1_w, conv2_w, Wc1, Wc2,
                                     emb, emb_w, emb_b, m1_w, m1_b, m2_w, m2_b,
                                     m3_w, m3_b, eo, b1v, b2v, b3v,
                                     c, g1S, g1Q, S);
    k_conv1<<<dim3(64, B_), 512, 0, stream>>>(c, Wc1, conv1_b, gn1_g, gn1_b,
                                              g1S, g1Q, y_buf, gnS, gnQ);
    k_conv2<<<dim3(64, B_), 512, 0, stream>>>(y_buf, Wc2, conv2_b, c, x, b1v, eo,
                                              gn2_g, gn2_b, gnS, gnQ, poolC2, S);
    k_bconv<<<dim3(64, B_), 512, 0, stream>>>(S, sgn, alpha, bconv_b, y_buf, bnS, bnQ);
    k_final<<<NCHW / 1024, 256, 0, stream>>>(y_buf, x, poolC2, bnS, bnQ, bn_g, bn_b,
                                             b2v, prelu_a, b3v, out);
}